// Round 7
// baseline (254.787 us; speedup 1.0000x reference)
//
#include <hip/hip_runtime.h>
#include <hip/hip_bf16.h>

#define LSEQ   16384
#define BATCH  32
#define NBS    64              // B*2 sequences
#define CHUNK4 896             // rows per chunk (256 threads x 4 rows)
#define NCH    19              // ceil(16384/896)
#define PL     976             // LDS plane stride in floats (rows -32..943 rel base)

// ---------------------------------------------------------------------------
// Fused 3-layer conv kernel, R=4 register blocking.
//   out[r][w] = relu(bias + sum_{cp=0..21} sum_{wi=0..9} in[r+cp-10][wi]*W[cp][wi-w+10])
// Rolling window: at iteration cp, registers hold rows r0+cp-10 .. r0+cp-7
// (xa..xd); one new row loaded per cp; 400 FMA per 10 LDS loads.
// LDS layout quad-deinterleaved: row r stored at slot ((r+32)&3)*244 + ((r+32)>>2)
// so lane t's accesses are stride-1 (conflict-free).
// Stage 3 writes PLAIN layout (float4, contiguous) for the top-k phase.
// ---------------------------------------------------------------------------

__device__ __forceinline__ void mac10x10(float acc[10], const float x[10],
                                         const float* __restrict__ wr) {
#pragma unroll
  for (int wi = 0; wi < 10; ++wi) {
    float xv = x[wi];
#pragma unroll
    for (int w = 0; w < 10; ++w) {
      acc[w] = fmaf(xv, wr[wi - w + 10], acc[w]);   // kw = wi-w+10 in [1,19]
    }
  }
}

// Merge two DESCENDING sorted 64-lists (one elem/lane) keeping top-64 of the
// union, result descending (bitonic-halver + 6-step clean).
__device__ __forceinline__ float bitonic_merge64(float a, float b, int lane) {
  float rb = __shfl(b, 63 - lane, 64);
  float m = fmaxf(a, rb);
#pragma unroll
  for (int j = 32; j > 0; j >>= 1) {
    float o = __shfl_xor(m, j, 64);
    m = ((lane & j) == 0) ? fmaxf(m, o) : fminf(m, o);
  }
  return m;
}

__device__ __forceinline__ float bitonic_sort64_desc(float v, int lane) {
#pragma unroll
  for (int k = 2; k <= 64; k <<= 1) {
#pragma unroll
    for (int j = k >> 1; j > 0; j >>= 1) {
      float o = __shfl_xor(v, j, 64);
      bool keepmax = (((lane & k) == 0) == ((lane & j) == 0));
      v = keepmax ? fmaxf(v, o) : fminf(v, o);
    }
  }
  return v;
}

__global__ __launch_bounds__(256, 2) void conv_fused_kernel(
    const int* __restrict__ inputs, const float* __restrict__ emb,
    const float* __restrict__ w1, const float* __restrict__ b1,
    const float* __restrict__ w2, const float* __restrict__ b2,
    const float* __restrict__ w3, const float* __restrict__ b3,
    float* __restrict__ cand /* [NBS*10][NCH][50] */) {
  __shared__ float bufA[10 * PL];
  __shared__ float bufB[10 * PL];

  int blk = blockIdx.x;
  int bs = blk / NCH;
  int chunk = blk - bs * NCH;
  int base = chunk * CHUNK4;
  int tid = threadIdx.x;

  // ---- gather: emb rows [base-32, base+944), 4 rows/thread, 244 threads ----
  const int* tokp = inputs + bs * LSEQ;
  if (tid < 244) {
#pragma unroll
    for (int j = 0; j < 4; ++j) {
      int g = base - 32 + 4 * tid + j;
      float v[10];
      if ((unsigned)g < (unsigned)LSEQ) {
        int tok = tokp[g];
        const float2* er = reinterpret_cast<const float2*>(emb + tok * 10);
#pragma unroll
        for (int k = 0; k < 5; ++k) { float2 t = er[k]; v[2 * k] = t.x; v[2 * k + 1] = t.y; }
      } else {
#pragma unroll
        for (int wi = 0; wi < 10; ++wi) v[wi] = 0.0f;
      }
#pragma unroll
      for (int wi = 0; wi < 10; ++wi) bufA[wi * PL + j * 244 + tid] = v[wi];
    }
  }
  __syncthreads();

  // ---- 3 conv stages ----
  // stage 0: outputs rows [-20, 920) (NT=235), A->B
  // stage 1: outputs rows [-10, 910) (NT=230), B->A
  // stage 2: outputs rows [  0, 896) (NT=224), A->B (plain layout)
#pragma unroll 1
  for (int stage = 0; stage < 3; ++stage) {
    const float* __restrict__ W = (stage == 0) ? w1 : (stage == 1) ? w2 : w3;
    const float bias = (stage == 0) ? b1[0] : (stage == 1) ? b2[0] : b3[0];
    const int lo = (stage == 0) ? -20 : (stage == 1) ? -10 : 0;
    const int NT = (stage == 0) ? 235 : (stage == 1) ? 230 : 224;
    const float* __restrict__ bin = (stage == 1) ? bufB : bufA;
    float* __restrict__ bout = (stage == 1) ? bufA : bufB;

    if (tid < NT) {
      int r0 = lo + 4 * tid;
      float a0[10], a1[10], a2[10], a3[10];
#pragma unroll
      for (int w = 0; w < 10; ++w) { a0[w] = bias; a1[w] = bias; a2[w] = bias; a3[w] = bias; }

      float xa[10], xb[10], xc[10], xd[10];
      // preload rows r0-10, r0-9, r0-8  (slot offset o = lo+22+{0,1,2})
      {
        int o = lo + 22, sl = (o & 3) * 244 + (o >> 2) + tid;
#pragma unroll
        for (int wi = 0; wi < 10; ++wi) xa[wi] = bin[wi * PL + sl];
      }
      {
        int o = lo + 23, sl = (o & 3) * 244 + (o >> 2) + tid;
#pragma unroll
        for (int wi = 0; wi < 10; ++wi) xb[wi] = bin[wi * PL + sl];
      }
      {
        int o = lo + 24, sl = (o & 3) * 244 + (o >> 2) + tid;
#pragma unroll
        for (int wi = 0; wi < 10; ++wi) xc[wi] = bin[wi * PL + sl];
      }

#pragma unroll 2
      for (int cp = 0; cp < 22; ++cp) {
        int o = lo + cp + 25;                       // new row r0+cp-7
        int sl = (o & 3) * 244 + (o >> 2) + tid;
#pragma unroll
        for (int wi = 0; wi < 10; ++wi) xd[wi] = bin[wi * PL + sl];
        const float* wp = W + cp * 22;
        mac10x10(a0, xa, wp);   // row r0+0 : kh=cp uses in[r0+cp-10]
        mac10x10(a1, xb, wp);   // row r0+1
        mac10x10(a2, xc, wp);   // row r0+2
        mac10x10(a3, xd, wp);   // row r0+3
#pragma unroll
        for (int wi = 0; wi < 10; ++wi) { xa[wi] = xb[wi]; xb[wi] = xc[wi]; xc[wi] = xd[wi]; }
      }

      if (stage < 2) {
        // interleaved write, relu + zero-mask OOB rows
#pragma unroll
        for (int j = 0; j < 4; ++j) {
          int g = base + r0 + j;
          bool valid = (unsigned)g < (unsigned)LSEQ;
          int oc = lo + j + 32;
          int sl = (oc & 3) * 244 + (oc >> 2) + tid;
          const float* acc = (j == 0) ? a0 : (j == 1) ? a1 : (j == 2) ? a2 : a3;
#pragma unroll
          for (int w = 0; w < 10; ++w)
            bout[w * PL + sl] = valid ? fmaxf(acc[w], 0.0f) : 0.0f;
        }
      } else {
        // plain layout, float4 per plane (validity uniform within a quad:
        // cutoff 16384-base is a multiple of 4)
        bool valid = (unsigned)(base + r0) < (unsigned)LSEQ;
#pragma unroll
        for (int w = 0; w < 10; ++w) {
          float4 o4;
          o4.x = valid ? fmaxf(a0[w], 0.0f) : 0.0f;
          o4.y = valid ? fmaxf(a1[w], 0.0f) : 0.0f;
          o4.z = valid ? fmaxf(a2[w], 0.0f) : 0.0f;
          o4.w = valid ? fmaxf(a3[w], 0.0f) : 0.0f;
          *reinterpret_cast<float4*>(&bout[w * PL + 4 * tid]) = o4;
        }
      }
    }
    if (stage == 2 && tid >= 224 && tid < 240) {
      // pad slots 896..959 with -1 (below any relu output)
      float4 p4 = make_float4(-1.0f, -1.0f, -1.0f, -1.0f);
#pragma unroll
      for (int w = 0; w < 10; ++w)
        *reinterpret_cast<float4*>(&bufB[w * PL + 4 * tid]) = p4;
    }
    __syncthreads();
  }

  // ---- per-chunk exact top-50 per channel, in-wave register bitonic ----
  // 960 slots = 15 segments of 64 (+1 pad seg). Waves 0,1: 3 channels;
  // waves 2,3: 2 channels.
  {
    int wv = tid >> 6, lane = tid & 63;
    for (int ci = 0; ci < 3; ++ci) {
      int ch = wv + ci * 4;
      if (ch >= 10) break;                   // wave-uniform branch
      float x[16];
#pragma unroll
      for (int s = 0; s < 15; ++s) x[s] = bufB[ch * PL + s * 64 + lane];
      x[15] = -1.0f;
#pragma unroll
      for (int s = 0; s < 15; ++s) x[s] = bitonic_sort64_desc(x[s], lane);
      float y0 = bitonic_merge64(x[0], x[1], lane);
      float y1 = bitonic_merge64(x[2], x[3], lane);
      float y2 = bitonic_merge64(x[4], x[5], lane);
      float y3 = bitonic_merge64(x[6], x[7], lane);
      float y4 = bitonic_merge64(x[8], x[9], lane);
      float y5 = bitonic_merge64(x[10], x[11], lane);
      float y6 = bitonic_merge64(x[12], x[13], lane);
      float y7 = bitonic_merge64(x[14], x[15], lane);
      float z0 = bitonic_merge64(y0, y1, lane);
      float z1 = bitonic_merge64(y2, y3, lane);
      float z2 = bitonic_merge64(y4, y5, lane);
      float z3 = bitonic_merge64(y6, y7, lane);
      float u0 = bitonic_merge64(z0, z1, lane);
      float u1 = bitonic_merge64(z2, z3, lane);
      float t  = bitonic_merge64(u0, u1, lane);
      if (lane < 50)
        cand[((bs * 10 + ch) * NCH + chunk) * 50 + lane] = t;
    }
  }
}

// ---------------------------------------------------------------------------
// Merge: per (bs, d), top-50 (sorted desc) of 19*50=950 chunk candidates.
// ---------------------------------------------------------------------------
__global__ __launch_bounds__(256) void merge_topk_kernel(
    const float* __restrict__ cand, float* __restrict__ fbuf) {
  __shared__ float ml[1024];
  int blk = blockIdx.x;            // bs*10 + d
  int tid = threadIdx.x;
  const float* src = cand + blk * (NCH * 50);
  for (int i = tid; i < 1024; i += 256) ml[i] = (i < NCH * 50) ? src[i] : -1.0f;
  for (int k = 2; k <= 1024; k <<= 1) {
    for (int j = k >> 1; j > 0; j >>= 1) {
      __syncthreads();
      for (int e = tid; e < 512; e += 256) {
        int lo = ((e & ~(j - 1)) << 1) | (e & (j - 1));
        int hi = lo | j;
        float a = ml[lo], b = ml[hi];
        bool desc = ((lo & k) == 0);
        if ((a < b) == desc) { ml[lo] = b; ml[hi] = a; }
      }
    }
  }
  __syncthreads();
  if (tid < 50) {
    int bs = blk / 10, d = blk - bs * 10;
    fbuf[bs * 500 + tid * 10 + d] = ml[tid];
  }
}

// ---------------------------------------------------------------------------
// Per-(batch, direction) MHA + sum over queries + final dense + softmax.
// ---------------------------------------------------------------------------
__global__ __launch_bounds__(256) void mha_kernel(
    const float* __restrict__ fbuf,
    const float* __restrict__ wq, const float* __restrict__ bq,
    const float* __restrict__ wk, const float* __restrict__ bk,
    const float* __restrict__ wv, const float* __restrict__ bv,
    const float* __restrict__ wo, const float* __restrict__ bo,
    const float* __restrict__ wf, const float* __restrict__ bf,
    float* __restrict__ out) {
  __shared__ float f[2][50][10];
  __shared__ float Qm[50][2][10];
  __shared__ float Km[50][2][10];
  __shared__ float Vm[50][2][10];
  __shared__ float A2[2][50][50];
  __shared__ float Abar[2][50];
  __shared__ float OS[2][10];
  __shared__ float rr[10];

  int blk = blockIdx.x, b = blk >> 1, dir = blk & 1;
  int qs = dir, ks = dir ^ 1;
  int tid = threadIdx.x;

  for (int i = tid; i < 1000; i += 256) (&f[0][0][0])[i] = fbuf[b * 1000 + i];
  __syncthreads();

  // projections: Q from f[qs], K/V from f[ks]
  for (int i = tid; i < 1000; i += 256) {
    int q = i / 20, rem = i - q * 20;
    int h = rem / 10, e = rem - h * 10;
    const float* fq = f[qs][q];
    const float* fk = f[ks][q];
    float aq = bq[h * 10 + e], ak = bk[h * 10 + e], av = bv[h * 10 + e];
#pragma unroll
    for (int dd = 0; dd < 10; ++dd) {
      int wIdx = dd * 20 + h * 10 + e;
      aq = fmaf(fq[dd], wq[wIdx], aq);
      ak = fmaf(fk[dd], wk[wIdx], ak);
      av = fmaf(fk[dd], wv[wIdx], av);
    }
    Qm[q][h][e] = aq; Km[q][h][e] = ak; Vm[q][h][e] = av;
  }
  __syncthreads();

  // softmax rows (h, q)
  for (int row = tid; row < 100; row += 256) {
    int h = row / 50, q = row - h * 50;
    const float* Qr = Qm[q][h];
    float lg[50], m = -1e30f;
#pragma unroll
    for (int s = 0; s < 50; ++s) {
      const float* Kr = Km[s][h];
      float t = 0.0f;
#pragma unroll
      for (int e = 0; e < 10; ++e) t = fmaf(Qr[e], Kr[e], t);
      t *= 0.31622776601683794f;   // 1/sqrt(10)
      lg[s] = t; m = fmaxf(m, t);
    }
    float sum = 0.0f;
#pragma unroll
    for (int s = 0; s < 50; ++s) { float p = __expf(lg[s] - m); lg[s] = p; sum += p; }
    float inv = 1.0f / sum;
#pragma unroll
    for (int s = 0; s < 50; ++s) A2[h][q][s] = lg[s] * inv;
  }
  __syncthreads();

  // Abar[h][s] = sum_q A[h][q][s]
  for (int i = tid; i < 100; i += 256) {
    int h = i / 50, s = i - h * 50;
    float t = 0.0f;
#pragma unroll
    for (int q = 0; q < 50; ++q) t += A2[h][q][s];
    Abar[h][s] = t;
  }
  __syncthreads();
  if (tid < 20) {
    int h = tid / 10, e = tid - h * 10;
    float t = 0.0f;
#pragma unroll
    for (int s = 0; s < 50; ++s) t += Abar[h][s] * Vm[s][h][e];
    OS[h][e] = t;
  }
  __syncthreads();
  if (tid < 10) {
    int dc = tid;
    float t = 50.0f * bo[dc];
#pragma unroll
    for (int h = 0; h < 2; ++h)
#pragma unroll
      for (int e = 0; e < 10; ++e) t = fmaf(OS[h][e], wo[h * 100 + e * 10 + dc], t);
    rr[dc] = t;
  }
  __syncthreads();
  if (tid == 0) {
    float l0 = bf[0], l1 = bf[1];
#pragma unroll
    for (int dd = 0; dd < 10; ++dd) {
      l0 = fmaf(rr[dd], wf[dd * 2 + 0], l0);
      l1 = fmaf(rr[dd], wf[dd * 2 + 1], l1);
    }
    float m = fmaxf(l0, l1);
    float e0 = expf(l0 - m), e1 = expf(l1 - m);
    float inv = 1.0f / (e0 + e1);
    out[(b * 2 + dir) * 2 + 0] = e0 * inv;
    out[(b * 2 + dir) * 2 + 1] = e1 * inv;
  }
}

// ---------------------------------------------------------------------------
extern "C" void kernel_launch(void* const* d_in, const int* in_sizes, int n_in,
                              void* d_out, int out_size, void* d_ws, size_t ws_size,
                              hipStream_t stream) {
  const int*   inputs = (const int*)d_in[0];
  const float* emb = (const float*)d_in[1];
  const float* w1 = (const float*)d_in[2];
  const float* b1 = (const float*)d_in[3];
  const float* w2 = (const float*)d_in[4];
  const float* b2 = (const float*)d_in[5];
  const float* w3 = (const float*)d_in[6];
  const float* b3 = (const float*)d_in[7];
  const float* wq = (const float*)d_in[8];
  const float* bq = (const float*)d_in[9];
  const float* wk = (const float*)d_in[10];
  const float* bk = (const float*)d_in[11];
  const float* wv = (const float*)d_in[12];
  const float* bv = (const float*)d_in[13];
  const float* wo = (const float*)d_in[14];
  const float* bo = (const float*)d_in[15];
  const float* wf = (const float*)d_in[16];
  const float* bf = (const float*)d_in[17];
  float* out = (float*)d_out;

  float* fbuf = (float*)d_ws;                 // 32000 floats
  float* cand = (float*)d_ws + 32768;         // 640*19*50 = 608000 floats

  hipLaunchKernelGGL(conv_fused_kernel, dim3(NBS * NCH), dim3(256), 0, stream,
                     inputs, emb, w1, b1, w2, b2, w3, b3, cand);
  hipLaunchKernelGGL(merge_topk_kernel, dim3(NBS * 10), dim3(256), 0, stream, cand, fbuf);
  hipLaunchKernelGGL(mha_kernel, dim3(NBS), dim3(256), 0, stream,
                     fbuf, wq, bq, wk, bk, wv, bv, wo, bo, wf, bf, out);
}

// Round 8
// 245.151 us; speedup vs baseline: 1.0393x; 1.0393x over previous
//
#include <hip/hip_runtime.h>
#include <hip/hip_bf16.h>

#define LSEQ   16384
#define BATCH  32
#define NBS    64              // B*2 sequences
#define CHUNK4 896             // rows per chunk (224 threads x 4 rows)
#define NCH    19              // ceil(16384/896)
#define PL     976             // LDS plane stride in floats (rows -32..943 rel base)

// ---------------------------------------------------------------------------
// Fused 3-layer conv kernel, R=4 register blocking, SINGLE LDS buffer.
//   out[r][w] = relu(bias + sum_{cp=0..21} sum_{wi=0..9} in[r+cp-10][wi]*W[cp][wi-w+10])
// Rolling window: at iteration cp, registers hold rows r0+cp-10 .. r0+cp-7;
// one new row loaded per cp; 400 FMA per 10 LDS loads.
// IN-PLACE stages: the cp-loop only READS the buffer (accumulating into
// registers); a barrier separates all reads from the relu/mask WRITES back
// into the same buffer (exact: block-wide reads complete before any write).
// LDS = 10 planes x 976 floats = 39 KB -> 4 blocks/CU (round 7's dual-buffer
// 78 KB halved residency and cost 30us).
// LDS layout quad-deinterleaved: row r at slot ((r+32)&3)*244 + ((r+32)>>2),
// so each thread's accesses are stride-1 across lanes (conflict-free).
// Stage 3 writes PLAIN layout (float4, contiguous) for the top-k phase.
// ---------------------------------------------------------------------------

__device__ __forceinline__ void mac10x10(float acc[10], const float x[10],
                                         const float* __restrict__ wr) {
#pragma unroll
  for (int wi = 0; wi < 10; ++wi) {
    float xv = x[wi];
#pragma unroll
    for (int w = 0; w < 10; ++w) {
      acc[w] = fmaf(xv, wr[wi - w + 10], acc[w]);   // kw = wi-w+10 in [1,19]
    }
  }
}

// Merge two DESCENDING sorted 64-lists (one elem/lane) keeping top-64 of the
// union, result descending (bitonic-halver + 6-step clean).
__device__ __forceinline__ float bitonic_merge64(float a, float b, int lane) {
  float rb = __shfl(b, 63 - lane, 64);
  float m = fmaxf(a, rb);
#pragma unroll
  for (int j = 32; j > 0; j >>= 1) {
    float o = __shfl_xor(m, j, 64);
    m = ((lane & j) == 0) ? fmaxf(m, o) : fminf(m, o);
  }
  return m;
}

__device__ __forceinline__ float bitonic_sort64_desc(float v, int lane) {
#pragma unroll
  for (int k = 2; k <= 64; k <<= 1) {
#pragma unroll
    for (int j = k >> 1; j > 0; j >>= 1) {
      float o = __shfl_xor(v, j, 64);
      bool keepmax = (((lane & k) == 0) == ((lane & j) == 0));
      v = keepmax ? fmaxf(v, o) : fminf(v, o);
    }
  }
  return v;
}

__global__ __launch_bounds__(256, 4) void conv_fused_kernel(
    const int* __restrict__ inputs, const float* __restrict__ emb,
    const float* __restrict__ w1, const float* __restrict__ b1,
    const float* __restrict__ w2, const float* __restrict__ b2,
    const float* __restrict__ w3, const float* __restrict__ b3,
    float* __restrict__ cand /* [NBS*10][NCH][50] */) {
  __shared__ float buf[10 * PL];     // 39 KB

  int blk = blockIdx.x;
  int bs = blk / NCH;
  int chunk = blk - bs * NCH;
  int base = chunk * CHUNK4;
  int tid = threadIdx.x;

  // ---- gather: emb rows [base-32, base+944), 4 rows/thread, 244 threads ----
  const int* tokp = inputs + bs * LSEQ;
  if (tid < 244) {
#pragma unroll
    for (int j = 0; j < 4; ++j) {
      int g = base - 32 + 4 * tid + j;
      float v[10];
      if ((unsigned)g < (unsigned)LSEQ) {
        int tok = tokp[g];
        const float2* er = reinterpret_cast<const float2*>(emb + tok * 10);
#pragma unroll
        for (int k = 0; k < 5; ++k) { float2 t = er[k]; v[2 * k] = t.x; v[2 * k + 1] = t.y; }
      } else {
#pragma unroll
        for (int wi = 0; wi < 10; ++wi) v[wi] = 0.0f;
      }
#pragma unroll
      for (int wi = 0; wi < 10; ++wi) buf[wi * PL + j * 244 + tid] = v[wi];
    }
  }
  __syncthreads();

  // ---- 3 conv stages, in-place ----
  // stage 0: outputs rows [-20, 920) (NT=235)
  // stage 1: outputs rows [-10, 910) (NT=230)
  // stage 2: outputs rows [  0, 896) (NT=224), plain layout
#pragma unroll 1
  for (int stage = 0; stage < 3; ++stage) {
    const float* __restrict__ W = (stage == 0) ? w1 : (stage == 1) ? w2 : w3;
    const float bias = (stage == 0) ? b1[0] : (stage == 1) ? b2[0] : b3[0];
    const int lo = (stage == 0) ? -20 : (stage == 1) ? -10 : 0;
    const int NT = (stage == 0) ? 235 : (stage == 1) ? 230 : 224;

    float a0[10], a1[10], a2[10], a3[10];
    int r0 = lo + 4 * tid;

    if (tid < NT) {
#pragma unroll
      for (int w = 0; w < 10; ++w) { a0[w] = bias; a1[w] = bias; a2[w] = bias; a3[w] = bias; }

      float xa[10], xb[10], xc[10], xd[10];
      // preload rows r0-10, r0-9, r0-8  (slot offset o = lo+22+{0,1,2})
      {
        int o = lo + 22, sl = (o & 3) * 244 + (o >> 2) + tid;
#pragma unroll
        for (int wi = 0; wi < 10; ++wi) xa[wi] = buf[wi * PL + sl];
      }
      {
        int o = lo + 23, sl = (o & 3) * 244 + (o >> 2) + tid;
#pragma unroll
        for (int wi = 0; wi < 10; ++wi) xb[wi] = buf[wi * PL + sl];
      }
      {
        int o = lo + 24, sl = (o & 3) * 244 + (o >> 2) + tid;
#pragma unroll
        for (int wi = 0; wi < 10; ++wi) xc[wi] = buf[wi * PL + sl];
      }

#pragma unroll 2
      for (int cp = 0; cp < 22; ++cp) {
        int o = lo + cp + 25;                       // new row r0+cp-7
        int sl = (o & 3) * 244 + (o >> 2) + tid;
#pragma unroll
        for (int wi = 0; wi < 10; ++wi) xd[wi] = buf[wi * PL + sl];
        const float* wp = W + cp * 22;
        mac10x10(a0, xa, wp);   // row r0+0 : kh=cp uses in[r0+cp-10]
        mac10x10(a1, xb, wp);   // row r0+1
        mac10x10(a2, xc, wp);   // row r0+2
        mac10x10(a3, xd, wp);   // row r0+3
#pragma unroll
        for (int wi = 0; wi < 10; ++wi) { xa[wi] = xb[wi]; xb[wi] = xc[wi]; xc[wi] = xd[wi]; }
      }
    }
    __syncthreads();   // ALL reads of this stage complete before any write

    if (tid < NT) {
      if (stage < 2) {
        // interleaved write, relu + zero-mask OOB rows
#pragma unroll
        for (int j = 0; j < 4; ++j) {
          int g = base + r0 + j;
          bool valid = (unsigned)g < (unsigned)LSEQ;
          int oc = lo + j + 32;
          int sl = (oc & 3) * 244 + (oc >> 2) + tid;
          const float* acc = (j == 0) ? a0 : (j == 1) ? a1 : (j == 2) ? a2 : a3;
#pragma unroll
          for (int w = 0; w < 10; ++w)
            buf[w * PL + sl] = valid ? fmaxf(acc[w], 0.0f) : 0.0f;
        }
      } else {
        // plain layout, float4 per plane (validity uniform within a quad:
        // cutoff 16384-base is a multiple of 4)
        bool valid = (unsigned)(base + r0) < (unsigned)LSEQ;
#pragma unroll
        for (int w = 0; w < 10; ++w) {
          float4 o4;
          o4.x = valid ? fmaxf(a0[w], 0.0f) : 0.0f;
          o4.y = valid ? fmaxf(a1[w], 0.0f) : 0.0f;
          o4.z = valid ? fmaxf(a2[w], 0.0f) : 0.0f;
          o4.w = valid ? fmaxf(a3[w], 0.0f) : 0.0f;
          *reinterpret_cast<float4*>(&buf[w * PL + 4 * tid]) = o4;
        }
      }
    }
    if (stage == 2 && tid >= 224 && tid < 240) {
      // pad slots 896..959 with -1 (below any relu output)
      float4 p4 = make_float4(-1.0f, -1.0f, -1.0f, -1.0f);
#pragma unroll
      for (int w = 0; w < 10; ++w)
        *reinterpret_cast<float4*>(&buf[w * PL + 4 * tid]) = p4;
    }
    __syncthreads();
  }

  // ---- per-chunk exact top-50 per channel, in-wave register bitonic ----
  // 960 slots = 15 segments of 64 (+1 constant pad seg). Waves 0,1: 3
  // channels; waves 2,3: 2 channels.
  {
    int wv = tid >> 6, lane = tid & 63;
    for (int ci = 0; ci < 3; ++ci) {
      int ch = wv + ci * 4;
      if (ch >= 10) break;                   // wave-uniform branch
      float x[16];
#pragma unroll
      for (int s = 0; s < 15; ++s) x[s] = buf[ch * PL + s * 64 + lane];
      x[15] = -1.0f;
#pragma unroll
      for (int s = 0; s < 15; ++s) x[s] = bitonic_sort64_desc(x[s], lane);
      float y0 = bitonic_merge64(x[0], x[1], lane);
      float y1 = bitonic_merge64(x[2], x[3], lane);
      float y2 = bitonic_merge64(x[4], x[5], lane);
      float y3 = bitonic_merge64(x[6], x[7], lane);
      float y4 = bitonic_merge64(x[8], x[9], lane);
      float y5 = bitonic_merge64(x[10], x[11], lane);
      float y6 = bitonic_merge64(x[12], x[13], lane);
      float y7 = bitonic_merge64(x[14], x[15], lane);
      float z0 = bitonic_merge64(y0, y1, lane);
      float z1 = bitonic_merge64(y2, y3, lane);
      float z2 = bitonic_merge64(y4, y5, lane);
      float z3 = bitonic_merge64(y6, y7, lane);
      float u0 = bitonic_merge64(z0, z1, lane);
      float u1 = bitonic_merge64(z2, z3, lane);
      float t  = bitonic_merge64(u0, u1, lane);
      if (lane < 50)
        cand[((bs * 10 + ch) * NCH + chunk) * 50 + lane] = t;
    }
  }
}

// ---------------------------------------------------------------------------
// Merge: per (bs, d), top-50 (sorted desc) of 19*50=950 chunk candidates.
// ---------------------------------------------------------------------------
__global__ __launch_bounds__(256) void merge_topk_kernel(
    const float* __restrict__ cand, float* __restrict__ fbuf) {
  __shared__ float ml[1024];
  int blk = blockIdx.x;            // bs*10 + d
  int tid = threadIdx.x;
  const float* src = cand + blk * (NCH * 50);
  for (int i = tid; i < 1024; i += 256) ml[i] = (i < NCH * 50) ? src[i] : -1.0f;
  for (int k = 2; k <= 1024; k <<= 1) {
    for (int j = k >> 1; j > 0; j >>= 1) {
      __syncthreads();
      for (int e = tid; e < 512; e += 256) {
        int lo = ((e & ~(j - 1)) << 1) | (e & (j - 1));
        int hi = lo | j;
        float a = ml[lo], b = ml[hi];
        bool desc = ((lo & k) == 0);
        if ((a < b) == desc) { ml[lo] = b; ml[hi] = a; }
      }
    }
  }
  __syncthreads();
  if (tid < 50) {
    int bs = blk / 10, d = blk - bs * 10;
    fbuf[bs * 500 + tid * 10 + d] = ml[tid];
  }
}

// ---------------------------------------------------------------------------
// Per-(batch, direction) MHA + sum over queries + final dense + softmax.
// ---------------------------------------------------------------------------
__global__ __launch_bounds__(256) void mha_kernel(
    const float* __restrict__ fbuf,
    const float* __restrict__ wq, const float* __restrict__ bq,
    const float* __restrict__ wk, const float* __restrict__ bk,
    const float* __restrict__ wv, const float* __restrict__ bv,
    const float* __restrict__ wo, const float* __restrict__ bo,
    const float* __restrict__ wf, const float* __restrict__ bf,
    float* __restrict__ out) {
  __shared__ float f[2][50][10];
  __shared__ float Qm[50][2][10];
  __shared__ float Km[50][2][10];
  __shared__ float Vm[50][2][10];
  __shared__ float A2[2][50][50];
  __shared__ float Abar[2][50];
  __shared__ float OS[2][10];
  __shared__ float rr[10];

  int blk = blockIdx.x, b = blk >> 1, dir = blk & 1;
  int qs = dir, ks = dir ^ 1;
  int tid = threadIdx.x;

  for (int i = tid; i < 1000; i += 256) (&f[0][0][0])[i] = fbuf[b * 1000 + i];
  __syncthreads();

  // projections: Q from f[qs], K/V from f[ks]
  for (int i = tid; i < 1000; i += 256) {
    int q = i / 20, rem = i - q * 20;
    int h = rem / 10, e = rem - h * 10;
    const float* fq = f[qs][q];
    const float* fk = f[ks][q];
    float aq = bq[h * 10 + e], ak = bk[h * 10 + e], av = bv[h * 10 + e];
#pragma unroll
    for (int dd = 0; dd < 10; ++dd) {
      int wIdx = dd * 20 + h * 10 + e;
      aq = fmaf(fq[dd], wq[wIdx], aq);
      ak = fmaf(fk[dd], wk[wIdx], ak);
      av = fmaf(fk[dd], wv[wIdx], av);
    }
    Qm[q][h][e] = aq; Km[q][h][e] = ak; Vm[q][h][e] = av;
  }
  __syncthreads();

  // softmax rows (h, q)
  for (int row = tid; row < 100; row += 256) {
    int h = row / 50, q = row - h * 50;
    const float* Qr = Qm[q][h];
    float lg[50], m = -1e30f;
#pragma unroll
    for (int s = 0; s < 50; ++s) {
      const float* Kr = Km[s][h];
      float t = 0.0f;
#pragma unroll
      for (int e = 0; e < 10; ++e) t = fmaf(Qr[e], Kr[e], t);
      t *= 0.31622776601683794f;   // 1/sqrt(10)
      lg[s] = t; m = fmaxf(m, t);
    }
    float sum = 0.0f;
#pragma unroll
    for (int s = 0; s < 50; ++s) { float p = __expf(lg[s] - m); lg[s] = p; sum += p; }
    float inv = 1.0f / sum;
#pragma unroll
    for (int s = 0; s < 50; ++s) A2[h][q][s] = lg[s] * inv;
  }
  __syncthreads();

  // Abar[h][s] = sum_q A[h][q][s]
  for (int i = tid; i < 100; i += 256) {
    int h = i / 50, s = i - h * 50;
    float t = 0.0f;
#pragma unroll
    for (int q = 0; q < 50; ++q) t += A2[h][q][s];
    Abar[h][s] = t;
  }
  __syncthreads();
  if (tid < 20) {
    int h = tid / 10, e = tid - h * 10;
    float t = 0.0f;
#pragma unroll
    for (int s = 0; s < 50; ++s) t += Abar[h][s] * Vm[s][h][e];
    OS[h][e] = t;
  }
  __syncthreads();
  if (tid < 10) {
    int dc = tid;
    float t = 50.0f * bo[dc];
#pragma unroll
    for (int h = 0; h < 2; ++h)
#pragma unroll
      for (int e = 0; e < 10; ++e) t = fmaf(OS[h][e], wo[h * 100 + e * 10 + dc], t);
    rr[dc] = t;
  }
  __syncthreads();
  if (tid == 0) {
    float l0 = bf[0], l1 = bf[1];
#pragma unroll
    for (int dd = 0; dd < 10; ++dd) {
      l0 = fmaf(rr[dd], wf[dd * 2 + 0], l0);
      l1 = fmaf(rr[dd], wf[dd * 2 + 1], l1);
    }
    float m = fmaxf(l0, l1);
    float e0 = expf(l0 - m), e1 = expf(l1 - m);
    float inv = 1.0f / (e0 + e1);
    out[(b * 2 + dir) * 2 + 0] = e0 * inv;
    out[(b * 2 + dir) * 2 + 1] = e1 * inv;
  }
}

// ---------------------------------------------------------------------------
extern "C" void kernel_launch(void* const* d_in, const int* in_sizes, int n_in,
                              void* d_out, int out_size, void* d_ws, size_t ws_size,
                              hipStream_t stream) {
  const int*   inputs = (const int*)d_in[0];
  const float* emb = (const float*)d_in[1];
  const float* w1 = (const float*)d_in[2];
  const float* b1 = (const float*)d_in[3];
  const float* w2 = (const float*)d_in[4];
  const float* b2 = (const float*)d_in[5];
  const float* w3 = (const float*)d_in[6];
  const float* b3 = (const float*)d_in[7];
  const float* wq = (const float*)d_in[8];
  const float* bq = (const float*)d_in[9];
  const float* wk = (const float*)d_in[10];
  const float* bk = (const float*)d_in[11];
  const float* wv = (const float*)d_in[12];
  const float* bv = (const float*)d_in[13];
  const float* wo = (const float*)d_in[14];
  const float* bo = (const float*)d_in[15];
  const float* wf = (const float*)d_in[16];
  const float* bf = (const float*)d_in[17];
  float* out = (float*)d_out;

  float* fbuf = (float*)d_ws;                 // 32000 floats
  float* cand = (float*)d_ws + 32768;         // 640*19*50 = 608000 floats

  hipLaunchKernelGGL(conv_fused_kernel, dim3(NBS * NCH), dim3(256), 0, stream,
                     inputs, emb, w1, b1, w2, b2, w3, b3, cand);
  hipLaunchKernelGGL(merge_topk_kernel, dim3(NBS * 10), dim3(256), 0, stream, cand, fbuf);
  hipLaunchKernelGGL(mha_kernel, dim3(NBS), dim3(256), 0, stream,
                     fbuf, wq, bq, wk, bk, wv, bv, wo, bo, wf, bf, out);
}

// Round 9
// 203.712 us; speedup vs baseline: 1.2507x; 1.2034x over previous
//
#include <hip/hip_runtime.h>
#include <hip/hip_bf16.h>

#define LSEQ   16384
#define BATCH  32
#define NBS    64              // B*2 sequences
#define CHUNK  448             // output rows per block
#define NCHK   37              // ceil(16384/448)
#define ROWS   536             // LDS plane rows: seq [base-32, base+504)
#define RS     24              // row stride in ushorts (48 B: 16 bf16 data + 8 pad)

typedef short v8s __attribute__((ext_vector_type(8)));   // 8 bf16 = 4 VGPR
typedef float v4f __attribute__((ext_vector_type(4)));   // MFMA acc

__device__ __forceinline__ unsigned short f2bf(float f) {   // RTNE f32->bf16
  unsigned u = __float_as_uint(f);
  unsigned r = u + 0x7FFFu + ((u >> 16) & 1u);
  return (unsigned short)(r >> 16);
}
__device__ __forceinline__ float bf2f(unsigned short h) {
  return __uint_as_float(((unsigned)h) << 16);
}

// ---------------------------------------------------------------------------
// B-fragment precompute: B[k=kh*16+wi][n] = W[kh][wi-n+10] (0 outside / n>=10),
// split v = hi(bf16) + lo(bf16). Fragment layout for mfma_f32_16x16x32_bf16
// B-operand: lane l holds B[k=32t+(l>>4)*8+j][col=l&15], j=0..7.
// Stored as [stage][t][lane][8] ushorts (16 B per lane -> coalesced loads).
// ---------------------------------------------------------------------------
__global__ __launch_bounds__(256) void bfrag_kernel(
    const float* __restrict__ w1, const float* __restrict__ w2,
    const float* __restrict__ w3,
    unsigned short* __restrict__ bh, unsigned short* __restrict__ bl) {
  int idx = blockIdx.x * 256 + threadIdx.x;   // (stage*11 + t)*64 + lane
  if (idx >= 3 * 11 * 64) return;
  int lane = idx & 63, rest = idx >> 6;
  int t = rest % 11, stage = rest / 11;
  const float* W = (stage == 0) ? w1 : (stage == 1) ? w2 : w3;
  int col = lane & 15;
  int kh = 2 * t + (lane >> 5);
  int wi0 = ((lane >> 4) & 1) * 8;
#pragma unroll
  for (int j = 0; j < 8; ++j) {
    int wi = wi0 + j;
    int kw = wi - col + 10;
    float v = (wi < 10 && col < 10 && kw >= 0 && kw < 22) ? W[kh * 22 + kw] : 0.0f;
    unsigned short h = f2bf(v);
    float lo = v - bf2f(h);
    bh[idx * 8 + j] = h;
    bl[idx * 8 + j] = f2bf(lo);
  }
}

// Merge two DESCENDING sorted 64-lists keeping top-64, result descending.
__device__ __forceinline__ float bitonic_merge64(float a, float b, int lane) {
  float rb = __shfl(b, 63 - lane, 64);
  float m = fmaxf(a, rb);
#pragma unroll
  for (int j = 32; j > 0; j >>= 1) {
    float o = __shfl_xor(m, j, 64);
    m = ((lane & j) == 0) ? fmaxf(m, o) : fminf(m, o);
  }
  return m;
}
__device__ __forceinline__ float bitonic_sort64_desc(float v, int lane) {
#pragma unroll
  for (int k = 2; k <= 64; k <<= 1) {
#pragma unroll
    for (int j = k >> 1; j > 0; j >>= 1) {
      float o = __shfl_xor(v, j, 64);
      bool keepmax = (((lane & k) == 0) == ((lane & j) == 0));
      v = keepmax ? fmaxf(v, o) : fminf(v, o);
    }
  }
  return v;
}

// ---------------------------------------------------------------------------
// Fused 3-layer conv via bf16 MFMA + in-wave bitonic top-50.
// A-fragment: lane l, k-step t reads 8 consecutive bf16 (one ds_read_b128)
// from input row (l&15)+2t+(l>>5)-10 rel tile, at wi0=((l>>4)&1)*8.
// In-place plane (reads in regs -> barrier -> writes). Stage tile ranges:
//   s0: 32 tiles @ -20  (covers [-20,492), reads [-30,503))
//   s1: 30 tiles @ -10  (covers [-10,470), reads [-20,481))
//   s2: 28 tiles @   0  (covers [0,448),   reads [-10,459))
// C/D layout: col=lane&15, row=(lane>>4)*4+reg (m89-verified).
// ---------------------------------------------------------------------------
__global__ __launch_bounds__(256) void conv_fused_kernel(
    const int* __restrict__ inputs, const float* __restrict__ emb,
    const float* __restrict__ b1, const float* __restrict__ b2,
    const float* __restrict__ b3,
    const unsigned short* __restrict__ bh, const unsigned short* __restrict__ bl,
    float* __restrict__ cand /* [NBS*10][NCHK][50] */) {
  __shared__ unsigned short plane[ROWS * RS];   // 25.7 KB

  int blk = blockIdx.x;
  int bs = blk / NCHK;
  int chunk = blk - bs * NCHK;
  int base = chunk * CHUNK;
  int tid = threadIdx.x;
  int lane = tid & 63, wave = tid >> 6;

  // ---- gather: emb rows seq [base-32, base+504) -> bf16 plane ----
  const int* tokp = inputs + bs * LSEQ;
  for (int i = tid; i < ROWS; i += 256) {
    int seq = base - 32 + i;
    v8s lo8 = (v8s)0, hi8 = (v8s)0;
    if ((unsigned)seq < (unsigned)LSEQ) {
      int tok = tokp[seq];
      const float2* er = reinterpret_cast<const float2*>(emb + tok * 10);
      float v[10];
#pragma unroll
      for (int k = 0; k < 5; ++k) { float2 t2 = er[k]; v[2 * k] = t2.x; v[2 * k + 1] = t2.y; }
#pragma unroll
      for (int j = 0; j < 8; ++j) lo8[j] = (short)f2bf(v[j]);
      hi8[0] = (short)f2bf(v[8]);
      hi8[1] = (short)f2bf(v[9]);
    }
    *reinterpret_cast<v8s*>(&plane[i * RS + 0]) = lo8;
    *reinterpret_cast<v8s*>(&plane[i * RS + 8]) = hi8;
  }
  __syncthreads();

  // lane-constant part of A address: row (l&15)+(l>>5)+22 (incl +32 plane
  // offset, -10 kh shift), elem offset wi0.
  const int laneA = ((lane & 15) + (lane >> 5) + 22) * RS + ((lane >> 4) & 1) * 8;
  const int col = lane & 15;
  const int rbase = (lane >> 4) * 4;

#pragma unroll 1
  for (int stage = 0; stage < 3; ++stage) {
    const int lo = (stage == 0) ? -20 : (stage == 1) ? -10 : 0;
    const int ntiles = (stage == 0) ? 32 : (stage == 1) ? 30 : 28;
    const float bias = (stage == 0) ? b1[0] : (stage == 1) ? b2[0] : b3[0];
    const int nt = (ntiles - wave + 3) >> 2;     // tiles wave+4m, m<nt

    v4f acc[8];
#pragma unroll
    for (int m = 0; m < 8; ++m)
#pragma unroll
      for (int j = 0; j < 4; ++j) acc[m][j] = 0.0f;

    const v8s* bhf = reinterpret_cast<const v8s*>(bh) + (stage * 11) * 64 + lane;
    const v8s* blf = reinterpret_cast<const v8s*>(bl) + (stage * 11) * 64 + lane;
    v8s bhc = bhf[0], blc = blf[0];

#pragma unroll 1
    for (int t = 0; t < 11; ++t) {
      v8s bhn = bhc, bln = blc;
      if (t < 10) { bhn = bhf[(t + 1) * 64]; bln = blf[(t + 1) * 64]; }
      const int toff = laneA + t * 2 * RS;
#pragma unroll
      for (int m = 0; m < 8; ++m) {
        if (m < nt) {
          int r0 = lo + (wave + 4 * m) * 16;
          v8s a = *reinterpret_cast<const v8s*>(&plane[toff + r0 * RS]);
          acc[m] = __builtin_amdgcn_mfma_f32_16x16x32_bf16(a, bhc, acc[m], 0, 0, 0);
          acc[m] = __builtin_amdgcn_mfma_f32_16x16x32_bf16(a, blc, acc[m], 0, 0, 0);
        }
      }
      bhc = bhn; blc = bln;
    }
    __syncthreads();   // all reads complete before in-place writes

#pragma unroll
    for (int m = 0; m < 8; ++m) {
      if (m < nt) {
        int r0 = lo + (wave + 4 * m) * 16;
#pragma unroll
        for (int j = 0; j < 4; ++j) {
          int rloc = r0 + rbase + j;
          int seq = base + rloc;
          float v = fmaxf(acc[m][j] + bias, 0.0f);
          bool ok = (col < 10) && ((unsigned)seq < (unsigned)LSEQ);
          plane[(rloc + 32) * RS + col] = ok ? f2bf(v) : (unsigned short)0;
        }
      }
    }
    __syncthreads();
  }

  // ---- per-chunk exact top-50 per channel (448 vals = 7 segs + pad) ----
  {
    for (int ci = 0; ci < 3; ++ci) {
      int ch = wave + ci * 4;
      if (ch >= 10) break;                   // wave-uniform
      float x[8];
#pragma unroll
      for (int s = 0; s < 7; ++s)
        x[s] = bf2f(plane[(32 + s * 64 + lane) * RS + ch]);
      x[7] = -1.0f;
#pragma unroll
      for (int s = 0; s < 7; ++s) x[s] = bitonic_sort64_desc(x[s], lane);
      float y0 = bitonic_merge64(x[0], x[1], lane);
      float y1 = bitonic_merge64(x[2], x[3], lane);
      float y2 = bitonic_merge64(x[4], x[5], lane);
      float y3 = bitonic_merge64(x[6], x[7], lane);
      float z0 = bitonic_merge64(y0, y1, lane);
      float z1 = bitonic_merge64(y2, y3, lane);
      float tt = bitonic_merge64(z0, z1, lane);
      if (lane < 50)
        cand[((bs * 10 + ch) * NCHK + chunk) * 50 + lane] = tt;
    }
  }
}

// ---------------------------------------------------------------------------
// Merge: per (bs, d), top-50 (sorted desc) of 37*50=1850 chunk candidates.
// (Round-2 verified version.)
// ---------------------------------------------------------------------------
__global__ __launch_bounds__(256) void merge_topk_kernel(
    const float* __restrict__ cand, float* __restrict__ fbuf) {
  __shared__ float ml[2048];
  int blk = blockIdx.x;            // bs*10 + d
  int tid = threadIdx.x;
  const float* src = cand + blk * (NCHK * 50);
  for (int i = tid; i < 2048; i += 256) ml[i] = (i < NCHK * 50) ? src[i] : -1.0f;
  for (int k = 2; k <= 2048; k <<= 1) {
    for (int j = k >> 1; j > 0; j >>= 1) {
      __syncthreads();
      for (int e = tid; e < 1024; e += 256) {
        int lo = ((e & ~(j - 1)) << 1) | (e & (j - 1));
        int hi = lo | j;
        float a = ml[lo], b = ml[hi];
        bool desc = ((lo & k) == 0);
        if ((a < b) == desc) { ml[lo] = b; ml[hi] = a; }
      }
    }
  }
  __syncthreads();
  if (tid < 50) {
    int bs = blk / 10, d = blk - bs * 10;
    fbuf[bs * 500 + tid * 10 + d] = ml[tid];
  }
}

// ---------------------------------------------------------------------------
// Per-(batch, direction) MHA + sum over queries + final dense + softmax.
// ---------------------------------------------------------------------------
__global__ __launch_bounds__(256) void mha_kernel(
    const float* __restrict__ fbuf,
    const float* __restrict__ wq, const float* __restrict__ bq,
    const float* __restrict__ wk, const float* __restrict__ bk,
    const float* __restrict__ wv, const float* __restrict__ bv,
    const float* __restrict__ wo, const float* __restrict__ bo,
    const float* __restrict__ wf, const float* __restrict__ bf,
    float* __restrict__ out) {
  __shared__ float f[2][50][10];
  __shared__ float Qm[50][2][10];
  __shared__ float Km[50][2][10];
  __shared__ float Vm[50][2][10];
  __shared__ float A2[2][50][50];
  __shared__ float Abar[2][50];
  __shared__ float OS[2][10];
  __shared__ float rr[10];

  int blk = blockIdx.x, b = blk >> 1, dir = blk & 1;
  int qs = dir, ks = dir ^ 1;
  int tid = threadIdx.x;

  for (int i = tid; i < 1000; i += 256) (&f[0][0][0])[i] = fbuf[b * 1000 + i];
  __syncthreads();

  for (int i = tid; i < 1000; i += 256) {
    int q = i / 20, rem = i - q * 20;
    int h = rem / 10, e = rem - h * 10;
    const float* fq = f[qs][q];
    const float* fk = f[ks][q];
    float aq = bq[h * 10 + e], ak = bk[h * 10 + e], av = bv[h * 10 + e];
#pragma unroll
    for (int dd = 0; dd < 10; ++dd) {
      int wIdx = dd * 20 + h * 10 + e;
      aq = fmaf(fq[dd], wq[wIdx], aq);
      ak = fmaf(fk[dd], wk[wIdx], ak);
      av = fmaf(fk[dd], wv[wIdx], av);
    }
    Qm[q][h][e] = aq; Km[q][h][e] = ak; Vm[q][h][e] = av;
  }
  __syncthreads();

  for (int row = tid; row < 100; row += 256) {
    int h = row / 50, q = row - h * 50;
    const float* Qr = Qm[q][h];
    float lg[50], m = -1e30f;
#pragma unroll
    for (int s = 0; s < 50; ++s) {
      const float* Kr = Km[s][h];
      float t = 0.0f;
#pragma unroll
      for (int e = 0; e < 10; ++e) t = fmaf(Qr[e], Kr[e], t);
      t *= 0.31622776601683794f;   // 1/sqrt(10)
      lg[s] = t; m = fmaxf(m, t);
    }
    float sum = 0.0f;
#pragma unroll
    for (int s = 0; s < 50; ++s) { float p = __expf(lg[s] - m); lg[s] = p; sum += p; }
    float inv = 1.0f / sum;
#pragma unroll
    for (int s = 0; s < 50; ++s) A2[h][q][s] = lg[s] * inv;
  }
  __syncthreads();

  for (int i = tid; i < 100; i += 256) {
    int h = i / 50, s = i - h * 50;
    float t = 0.0f;
#pragma unroll
    for (int q = 0; q < 50; ++q) t += A2[h][q][s];
    Abar[h][s] = t;
  }
  __syncthreads();
  if (tid < 20) {
    int h = tid / 10, e = tid - h * 10;
    float t = 0.0f;
#pragma unroll
    for (int s = 0; s < 50; ++s) t += Abar[h][s] * Vm[s][h][e];
    OS[h][e] = t;
  }
  __syncthreads();
  if (tid < 10) {
    int dc = tid;
    float t = 50.0f * bo[dc];
#pragma unroll
    for (int h = 0; h < 2; ++h)
#pragma unroll
      for (int e = 0; e < 10; ++e) t = fmaf(OS[h][e], wo[h * 100 + e * 10 + dc], t);
    rr[dc] = t;
  }
  __syncthreads();
  if (tid == 0) {
    float l0 = bf[0], l1 = bf[1];
#pragma unroll
    for (int dd = 0; dd < 10; ++dd) {
      l0 = fmaf(rr[dd], wf[dd * 2 + 0], l0);
      l1 = fmaf(rr[dd], wf[dd * 2 + 1], l1);
    }
    float m = fmaxf(l0, l1);
    float e0 = expf(l0 - m), e1 = expf(l1 - m);
    float inv = 1.0f / (e0 + e1);
    out[(b * 2 + dir) * 2 + 0] = e0 * inv;
    out[(b * 2 + dir) * 2 + 1] = e1 * inv;
  }
}

// ---------------------------------------------------------------------------
extern "C" void kernel_launch(void* const* d_in, const int* in_sizes, int n_in,
                              void* d_out, int out_size, void* d_ws, size_t ws_size,
                              hipStream_t stream) {
  const int*   inputs = (const int*)d_in[0];
  const float* emb = (const float*)d_in[1];
  const float* w1 = (const float*)d_in[2];
  const float* b1 = (const float*)d_in[3];
  const float* w2 = (const float*)d_in[4];
  const float* b2 = (const float*)d_in[5];
  const float* w3 = (const float*)d_in[6];
  const float* b3 = (const float*)d_in[7];
  const float* wq = (const float*)d_in[8];
  const float* bq = (const float*)d_in[9];
  const float* wk = (const float*)d_in[10];
  const float* bk = (const float*)d_in[11];
  const float* wv = (const float*)d_in[12];
  const float* bv = (const float*)d_in[13];
  const float* wo = (const float*)d_in[14];
  const float* bo = (const float*)d_in[15];
  const float* wf = (const float*)d_in[16];
  const float* bf = (const float*)d_in[17];
  float* out = (float*)d_out;

  float* fbuf = (float*)d_ws;                         // 32000 floats
  float* cand = (float*)d_ws + 32768;                 // 640*37*50 = 1,184,000 floats
  unsigned short* bh = (unsigned short*)((float*)d_ws + 1216768);   // 16896 u16
  unsigned short* bl = bh + 16896;

  hipLaunchKernelGGL(bfrag_kernel, dim3(9), dim3(256), 0, stream, w1, w2, w3, bh, bl);
  hipLaunchKernelGGL(conv_fused_kernel, dim3(NBS * NCHK), dim3(256), 0, stream,
                     inputs, emb, b1, b2, b3, bh, bl, cand);
  hipLaunchKernelGGL(merge_topk_kernel, dim3(NBS * 10), dim3(256), 0, stream, cand, fbuf);
  hipLaunchKernelGGL(mha_kernel, dim3(NBS), dim3(256), 0, stream,
                     fbuf, wq, bq, wk, bk, wv, bv, wo, bo, wf, bf, out);
}

// Round 10
// 190.249 us; speedup vs baseline: 1.3392x; 1.0708x over previous
//
#include <hip/hip_runtime.h>
#include <hip/hip_bf16.h>

#define LSEQ   16384
#define BATCH  32
#define NBS    64              // B*2 sequences
#define NW     8000
#define CHUNK  448             // output rows per block
#define NCHK   37              // ceil(16384/448)
#define ROWS   536             // LDS plane rows: seq [base-32, base+504)
#define RS     24              // row stride in ushorts (48 B: 16 bf16 data + 8 pad)

typedef short v8s __attribute__((ext_vector_type(8)));   // 8 bf16 = 4 VGPR
typedef float v4f __attribute__((ext_vector_type(4)));   // MFMA acc

__device__ __forceinline__ unsigned short f2bf(float f) {   // RTNE f32->bf16
  unsigned u = __float_as_uint(f);
  unsigned r = u + 0x7FFFu + ((u >> 16) & 1u);
  return (unsigned short)(r >> 16);
}
__device__ __forceinline__ float bf2f(unsigned short h) {
  return __uint_as_float(((unsigned)h) << 16);
}
__device__ __forceinline__ unsigned short cvt_bf16(float v) {  // HW cvt (packed-friendly)
  __hip_bfloat16 hb = __float2bfloat16(v);
  unsigned short us;
  __builtin_memcpy(&us, &hb, 2);
  return us;
}

// ---------------------------------------------------------------------------
// One-time: emb (f32 [NW+1][10]) -> bf16 table [NW+1][16] (elems 10..15 = 0).
// Conv gather then copies raw ushorts (no per-block conversions).
// ---------------------------------------------------------------------------
__global__ __launch_bounds__(256) void emb16_kernel(
    const float* __restrict__ emb, unsigned short* __restrict__ emb16) {
  int r = blockIdx.x * 256 + threadIdx.x;
  if (r > NW) return;
  const float2* er = reinterpret_cast<const float2*>(emb + r * 10);
  float v[10];
#pragma unroll
  for (int k = 0; k < 5; ++k) { float2 t2 = er[k]; v[2 * k] = t2.x; v[2 * k + 1] = t2.y; }
  v8s lo8 = (v8s)0, hi8 = (v8s)0;
#pragma unroll
  for (int j = 0; j < 8; ++j) lo8[j] = (short)f2bf(v[j]);
  hi8[0] = (short)f2bf(v[8]);
  hi8[1] = (short)f2bf(v[9]);
  v8s* dst = reinterpret_cast<v8s*>(emb16 + r * 16);
  dst[0] = lo8;
  dst[1] = hi8;
}

// ---------------------------------------------------------------------------
// B-fragment precompute: B[k=kh*16+wi][n] = W[kh][wi-n+10] (0 outside / n>=10),
// single bf16 (no lo-correction). Fragment layout for mfma_f32_16x16x32_bf16
// B-operand: lane l holds B[k=32t+(l>>4)*8+j][col=l&15], j=0..7.
// ---------------------------------------------------------------------------
__global__ __launch_bounds__(256) void bfrag_kernel(
    const float* __restrict__ w1, const float* __restrict__ w2,
    const float* __restrict__ w3, unsigned short* __restrict__ bh) {
  int idx = blockIdx.x * 256 + threadIdx.x;   // (stage*11 + t)*64 + lane
  if (idx >= 3 * 11 * 64) return;
  int lane = idx & 63, rest = idx >> 6;
  int t = rest % 11, stage = rest / 11;
  const float* W = (stage == 0) ? w1 : (stage == 1) ? w2 : w3;
  int col = lane & 15;
  int kh = 2 * t + (lane >> 5);
  int wi0 = ((lane >> 4) & 1) * 8;
#pragma unroll
  for (int j = 0; j < 8; ++j) {
    int wi = wi0 + j;
    int kw = wi - col + 10;
    float v = (wi < 10 && col < 10 && kw >= 0 && kw < 22) ? W[kh * 22 + kw] : 0.0f;
    bh[idx * 8 + j] = f2bf(v);
  }
}

// Merge two DESCENDING sorted 64-lists keeping top-64, result descending.
__device__ __forceinline__ float bitonic_merge64(float a, float b, int lane) {
  float rb = __shfl(b, 63 - lane, 64);
  float m = fmaxf(a, rb);
#pragma unroll
  for (int j = 32; j > 0; j >>= 1) {
    float o = __shfl_xor(m, j, 64);
    m = ((lane & j) == 0) ? fmaxf(m, o) : fminf(m, o);
  }
  return m;
}
__device__ __forceinline__ float bitonic_sort64_desc(float v, int lane) {
#pragma unroll
  for (int k = 2; k <= 64; k <<= 1) {
#pragma unroll
    for (int j = k >> 1; j > 0; j >>= 1) {
      float o = __shfl_xor(v, j, 64);
      bool keepmax = (((lane & k) == 0) == ((lane & j) == 0));
      v = keepmax ? fmaxf(v, o) : fminf(v, o);
    }
  }
  return v;
}

// ---------------------------------------------------------------------------
// Fused 3-layer conv via bf16 MFMA + in-wave bitonic top-50 (round-9 verified
// structure; single-B MFMA, table gather, HW cvt epilogue).
// ---------------------------------------------------------------------------
__global__ __launch_bounds__(256) void conv_fused_kernel(
    const int* __restrict__ inputs, const unsigned short* __restrict__ emb16,
    const float* __restrict__ b1, const float* __restrict__ b2,
    const float* __restrict__ b3,
    const unsigned short* __restrict__ bh,
    float* __restrict__ cand /* [NBS*10][NCHK][50] */) {
  __shared__ unsigned short plane[ROWS * RS];   // 25.7 KB

  int blk = blockIdx.x;
  int bs = blk / NCHK;
  int chunk = blk - bs * NCHK;
  int base = chunk * CHUNK;
  int tid = threadIdx.x;
  int lane = tid & 63, wave = tid >> 6;

  // ---- gather: copy bf16 emb rows for seq [base-32, base+504) ----
  const int* tokp = inputs + bs * LSEQ;
  for (int i = tid; i < ROWS; i += 256) {
    int seq = base - 32 + i;
    v8s lo8 = (v8s)0, hi8 = (v8s)0;
    if ((unsigned)seq < (unsigned)LSEQ) {
      int tok = tokp[seq];
      const v8s* er = reinterpret_cast<const v8s*>(emb16 + tok * 16);
      lo8 = er[0];
      hi8 = er[1];
    }
    *reinterpret_cast<v8s*>(&plane[i * RS + 0]) = lo8;
    *reinterpret_cast<v8s*>(&plane[i * RS + 8]) = hi8;
  }
  __syncthreads();

  // lane-constant A address part: row (l&15)+(l>>5)+22 (incl +32 plane offset,
  // -10 kh shift), elem offset wi0 = ((l>>4)&1)*8.
  const int laneA = ((lane & 15) + (lane >> 5) + 22) * RS + ((lane >> 4) & 1) * 8;
  const int col = lane & 15;
  const int rbase = (lane >> 4) * 4;

#pragma unroll 1
  for (int stage = 0; stage < 3; ++stage) {
    const int lo = (stage == 0) ? -20 : (stage == 1) ? -10 : 0;
    const int ntiles = (stage == 0) ? 32 : (stage == 1) ? 30 : 28;
    const float bias = (stage == 0) ? b1[0] : (stage == 1) ? b2[0] : b3[0];
    const int nt = (ntiles - wave + 3) >> 2;     // tiles wave+4m, m<nt

    v4f acc[8];
#pragma unroll
    for (int m = 0; m < 8; ++m)
#pragma unroll
      for (int j = 0; j < 4; ++j) acc[m][j] = 0.0f;

    const v8s* bhf = reinterpret_cast<const v8s*>(bh) + (stage * 11) * 64 + lane;
    v8s bhc = bhf[0];

#pragma unroll 1
    for (int t = 0; t < 11; ++t) {
      v8s bhn = bhc;
      if (t < 10) bhn = bhf[(t + 1) * 64];
      const int toff = laneA + t * 2 * RS;
#pragma unroll
      for (int m = 0; m < 8; ++m) {
        if (m < nt) {
          int r0 = lo + (wave + 4 * m) * 16;
          v8s a = *reinterpret_cast<const v8s*>(&plane[toff + r0 * RS]);
          acc[m] = __builtin_amdgcn_mfma_f32_16x16x32_bf16(a, bhc, acc[m], 0, 0, 0);
        }
      }
      bhc = bhn;
    }
    __syncthreads();   // all reads complete before in-place writes

#pragma unroll
    for (int m = 0; m < 8; ++m) {
      if (m < nt) {
        int r0 = lo + (wave + 4 * m) * 16;
#pragma unroll
        for (int j = 0; j < 4; ++j) {
          int rloc = r0 + rbase + j;
          int seq = base + rloc;
          unsigned short us = cvt_bf16(fmaxf(acc[m][j] + bias, 0.0f));
          bool ok = (col < 10) && ((unsigned)seq < (unsigned)LSEQ);
          plane[(rloc + 32) * RS + col] = ok ? us : (unsigned short)0;
        }
      }
    }
    __syncthreads();
  }

  // ---- per-chunk exact top-50 per channel (448 vals = 7 segs of 64) ----
  {
    for (int ci = 0; ci < 3; ++ci) {
      int ch = wave + ci * 4;
      if (ch >= 10) break;                   // wave-uniform
      float x[7];
#pragma unroll
      for (int s = 0; s < 7; ++s)
        x[s] = bf2f(plane[(32 + s * 64 + lane) * RS + ch]);
#pragma unroll
      for (int s = 0; s < 7; ++s) x[s] = bitonic_sort64_desc(x[s], lane);
      float y0 = bitonic_merge64(x[0], x[1], lane);
      float y1 = bitonic_merge64(x[2], x[3], lane);
      float y2 = bitonic_merge64(x[4], x[5], lane);
      float z0 = bitonic_merge64(y0, y1, lane);
      float z1 = bitonic_merge64(y2, x[6], lane);
      float tt = bitonic_merge64(z0, z1, lane);
      if (lane < 50)
        cand[((bs * 10 + ch) * NCHK + chunk) * 50 + lane] = tt;
    }
  }
}

// ---------------------------------------------------------------------------
// Merge: per (bs, d), top-50 (sorted desc) of 37*50=1850 chunk candidates.
// ---------------------------------------------------------------------------
__global__ __launch_bounds__(256) void merge_topk_kernel(
    const float* __restrict__ cand, float* __restrict__ fbuf) {
  __shared__ float ml[2048];
  int blk = blockIdx.x;            // bs*10 + d
  int tid = threadIdx.x;
  const float* src = cand + blk * (NCHK * 50);
  for (int i = tid; i < 2048; i += 256) ml[i] = (i < NCHK * 50) ? src[i] : -1.0f;
  for (int k = 2; k <= 2048; k <<= 1) {
    for (int j = k >> 1; j > 0; j >>= 1) {
      __syncthreads();
      for (int e = tid; e < 1024; e += 256) {
        int lo = ((e & ~(j - 1)) << 1) | (e & (j - 1));
        int hi = lo | j;
        float a = ml[lo], b = ml[hi];
        bool desc = ((lo & k) == 0);
        if ((a < b) == desc) { ml[lo] = b; ml[hi] = a; }
      }
    }
  }
  __syncthreads();
  if (tid < 50) {
    int bs = blk / 10, d = blk - bs * 10;
    fbuf[bs * 500 + tid * 10 + d] = ml[tid];
  }
}

// ---------------------------------------------------------------------------
// Per-(batch, direction) MHA + sum over queries + final dense + softmax.
// ---------------------------------------------------------------------------
__global__ __launch_bounds__(256) void mha_kernel(
    const float* __restrict__ fbuf,
    const float* __restrict__ wq, const float* __restrict__ bq,
    const float* __restrict__ wk, const float* __restrict__ bk,
    const float* __restrict__ wv, const float* __restrict__ bv,
    const float* __restrict__ wo, const float* __restrict__ bo,
    const float* __restrict__ wf, const float* __restrict__ bf,
    float* __restrict__ out) {
  __shared__ float f[2][50][10];
  __shared__ float Qm[50][2][10];
  __shared__ float Km[50][2][10];
  __shared__ float Vm[50][2][10];
  __shared__ float A2[2][50][50];
  __shared__ float Abar[2][50];
  __shared__ float OS[2][10];
  __shared__ float rr[10];

  int blk = blockIdx.x, b = blk >> 1, dir = blk & 1;
  int qs = dir, ks = dir ^ 1;
  int tid = threadIdx.x;

  for (int i = tid; i < 1000; i += 256) (&f[0][0][0])[i] = fbuf[b * 1000 + i];
  __syncthreads();

  for (int i = tid; i < 1000; i += 256) {
    int q = i / 20, rem = i - q * 20;
    int h = rem / 10, e = rem - h * 10;
    const float* fq = f[qs][q];
    const float* fk = f[ks][q];
    float aq = bq[h * 10 + e], ak = bk[h * 10 + e], av = bv[h * 10 + e];
#pragma unroll
    for (int dd = 0; dd < 10; ++dd) {
      int wIdx = dd * 20 + h * 10 + e;
      aq = fmaf(fq[dd], wq[wIdx], aq);
      ak = fmaf(fk[dd], wk[wIdx], ak);
      av = fmaf(fk[dd], wv[wIdx], av);
    }
    Qm[q][h][e] = aq; Km[q][h][e] = ak; Vm[q][h][e] = av;
  }
  __syncthreads();

  for (int row = tid; row < 100; row += 256) {
    int h = row / 50, q = row - h * 50;
    const float* Qr = Qm[q][h];
    float lg[50], m = -1e30f;
#pragma unroll
    for (int s = 0; s < 50; ++s) {
      const float* Kr = Km[s][h];
      float t = 0.0f;
#pragma unroll
      for (int e = 0; e < 10; ++e) t = fmaf(Qr[e], Kr[e], t);
      t *= 0.31622776601683794f;   // 1/sqrt(10)
      lg[s] = t; m = fmaxf(m, t);
    }
    float sum = 0.0f;
#pragma unroll
    for (int s = 0; s < 50; ++s) { float p = __expf(lg[s] - m); lg[s] = p; sum += p; }
    float inv = 1.0f / sum;
#pragma unroll
    for (int s = 0; s < 50; ++s) A2[h][q][s] = lg[s] * inv;
  }
  __syncthreads();

  for (int i = tid; i < 100; i += 256) {
    int h = i / 50, s = i - h * 50;
    float t = 0.0f;
#pragma unroll
    for (int q = 0; q < 50; ++q) t += A2[h][q][s];
    Abar[h][s] = t;
  }
  __syncthreads();
  if (tid < 20) {
    int h = tid / 10, e = tid - h * 10;
    float t = 0.0f;
#pragma unroll
    for (int s = 0; s < 50; ++s) t += Abar[h][s] * Vm[s][h][e];
    OS[h][e] = t;
  }
  __syncthreads();
  if (tid < 10) {
    int dc = tid;
    float t = 50.0f * bo[dc];
#pragma unroll
    for (int h = 0; h < 2; ++h)
#pragma unroll
      for (int e = 0; e < 10; ++e) t = fmaf(OS[h][e], wo[h * 100 + e * 10 + dc], t);
    rr[dc] = t;
  }
  __syncthreads();
  if (tid == 0) {
    float l0 = bf[0], l1 = bf[1];
#pragma unroll
    for (int dd = 0; dd < 10; ++dd) {
      l0 = fmaf(rr[dd], wf[dd * 2 + 0], l0);
      l1 = fmaf(rr[dd], wf[dd * 2 + 1], l1);
    }
    float m = fmaxf(l0, l1);
    float e0 = expf(l0 - m), e1 = expf(l1 - m);
    float inv = 1.0f / (e0 + e1);
    out[(b * 2 + dir) * 2 + 0] = e0 * inv;
    out[(b * 2 + dir) * 2 + 1] = e1 * inv;
  }
}

// ---------------------------------------------------------------------------
extern "C" void kernel_launch(void* const* d_in, const int* in_sizes, int n_in,
                              void* d_out, int out_size, void* d_ws, size_t ws_size,
                              hipStream_t stream) {
  const int*   inputs = (const int*)d_in[0];
  const float* emb = (const float*)d_in[1];
  const float* w1 = (const float*)d_in[2];
  const float* b1 = (const float*)d_in[3];
  const float* w2 = (const float*)d_in[4];
  const float* b2 = (const float*)d_in[5];
  const float* w3 = (const float*)d_in[6];
  const float* b3 = (const float*)d_in[7];
  const float* wq = (const float*)d_in[8];
  const float* bq = (const float*)d_in[9];
  const float* wk = (const float*)d_in[10];
  const float* bk = (const float*)d_in[11];
  const float* wv = (const float*)d_in[12];
  const float* bv = (const float*)d_in[13];
  const float* wo = (const float*)d_in[14];
  const float* bo = (const float*)d_in[15];
  const float* wf = (const float*)d_in[16];
  const float* bf = (const float*)d_in[17];
  float* out = (float*)d_out;

  float* fbuf = (float*)d_ws;                         // 32768 f32
  float* cand = (float*)d_ws + 32768;                 // 640*37*50 = 1,184,000 f32
  unsigned short* bh = (unsigned short*)((float*)d_ws + 1216768);   // 16896 u16
  unsigned short* emb16 = bh + 16896;                 // 8001*16 u16 (16B-aligned)

  hipLaunchKernelGGL(emb16_kernel, dim3(32), dim3(256), 0, stream, emb, emb16);
  hipLaunchKernelGGL(bfrag_kernel, dim3(9), dim3(256), 0, stream, w1, w2, w3, bh);
  hipLaunchKernelGGL(conv_fused_kernel, dim3(NBS * NCHK), dim3(256), 0, stream,
                     inputs, emb16, b1, b2, b3, bh, cand);
  hipLaunchKernelGGL(merge_topk_kernel, dim3(NBS * 10), dim3(256), 0, stream, cand, fbuf);
  hipLaunchKernelGGL(mha_kernel, dim3(NBS), dim3(256), 0, stream,
                     fbuf, wq, bq, wk, bk, wv, bv, wo, bo, wf, bf, out);
}

// Round 12
// 173.858 us; speedup vs baseline: 1.4655x; 1.0943x over previous
//
#include <hip/hip_runtime.h>
#include <hip/hip_bf16.h>

#define LSEQ   16384
#define BATCH  32
#define NBS    64              // B*2 sequences
#define NW     8000
#define CHUNK  448             // output rows per block
#define NCHK   37              // ceil(16384/448)
#define ROWS   536             // LDS plane rows: seq [base-32, base+504)
#define RS     24              // row stride in ushorts (48 B: 16 bf16 data + 8 pad)

typedef short v8s __attribute__((ext_vector_type(8)));   // 8 bf16 = 4 VGPR
typedef float v4f __attribute__((ext_vector_type(4)));   // MFMA acc
typedef _Float16 hf2 __attribute__((ext_vector_type(2)));  // packed f16 pair

__device__ __forceinline__ unsigned short f2bf(float f) {   // RTNE f32->bf16
  unsigned u = __float_as_uint(f);
  unsigned r = u + 0x7FFFu + ((u >> 16) & 1u);
  return (unsigned short)(r >> 16);
}
__device__ __forceinline__ unsigned short cvt_bf16(float v) {  // HW cvt
  __hip_bfloat16 hb = __float2bfloat16(v);
  unsigned short us;
  __builtin_memcpy(&us, &hb, 2);
  return us;
}

// ---------------------------------------------------------------------------
// One-time: emb (f32 [NW+1][10]) -> bf16 table [NW+1][16] (elems 10..15 = 0).
// ---------------------------------------------------------------------------
__global__ __launch_bounds__(256) void emb16_kernel(
    const float* __restrict__ emb, unsigned short* __restrict__ emb16) {
  int r = blockIdx.x * 256 + threadIdx.x;
  if (r > NW) return;
  const float2* er = reinterpret_cast<const float2*>(emb + r * 10);
  float v[10];
#pragma unroll
  for (int k = 0; k < 5; ++k) { float2 t2 = er[k]; v[2 * k] = t2.x; v[2 * k + 1] = t2.y; }
  v8s lo8 = (v8s)0, hi8 = (v8s)0;
#pragma unroll
  for (int j = 0; j < 8; ++j) lo8[j] = (short)f2bf(v[j]);
  hi8[0] = (short)f2bf(v[8]);
  hi8[1] = (short)f2bf(v[9]);
  v8s* dst = reinterpret_cast<v8s*>(emb16 + r * 16);
  dst[0] = lo8;
  dst[1] = hi8;
}

// ---------------------------------------------------------------------------
// B-fragment precompute: B[k=kh*16+wi][n] = W[kh][wi-n+10] (0 outside / n>=10).
// mfma_f32_16x16x32_bf16 B-operand: lane l holds B[k=32t+(l>>4)*8+j][col=l&15].
// ---------------------------------------------------------------------------
__global__ __launch_bounds__(256) void bfrag_kernel(
    const float* __restrict__ w1, const float* __restrict__ w2,
    const float* __restrict__ w3, unsigned short* __restrict__ bh) {
  int idx = blockIdx.x * 256 + threadIdx.x;   // (stage*11 + t)*64 + lane
  if (idx >= 3 * 11 * 64) return;
  int lane = idx & 63, rest = idx >> 6;
  int t = rest % 11, stage = rest / 11;
  const float* W = (stage == 0) ? w1 : (stage == 1) ? w2 : w3;
  int col = lane & 15;
  int kh = 2 * t + (lane >> 5);
  int wi0 = ((lane >> 4) & 1) * 8;
#pragma unroll
  for (int j = 0; j < 8; ++j) {
    int wi = wi0 + j;
    int kw = wi - col + 10;
    float v = (wi < 10 && col < 10 && kw >= 0 && kw < 22) ? W[kh * 22 + kw] : 0.0f;
    bh[idx * 8 + j] = f2bf(v);
  }
}

// ---------------------------------------------------------------------------
// Packed-pair (two channels per u32, f16x2) bitonic primitives.
// Post-relu values are >=0 and << 65504, and already bf16-quantized, so
// bf16 -> f16 is EXACT and order-preserving. Both halves sort in the same
// direction -> one select serves both. __builtin_elementwise_max/min on
// native f16x2 vectors lower to v_pk_max_f16 / v_pk_min_f16 (avoids the
// __hmax2 fp16/bf16 overload collision that broke round 11's compile).
// ---------------------------------------------------------------------------
__device__ __forceinline__ unsigned h2max_u(unsigned a, unsigned b) {
  hf2 r = __builtin_elementwise_max(__builtin_bit_cast(hf2, a),
                                    __builtin_bit_cast(hf2, b));
  return __builtin_bit_cast(unsigned, r);
}
__device__ __forceinline__ unsigned h2min_u(unsigned a, unsigned b) {
  hf2 r = __builtin_elementwise_min(__builtin_bit_cast(hf2, a),
                                    __builtin_bit_cast(hf2, b));
  return __builtin_bit_cast(unsigned, r);
}

// Sort 64 packed pairs across the wave, both halves descending.
__device__ __forceinline__ unsigned bsort64_h2(unsigned v, int lane) {
#pragma unroll
  for (int k = 2; k <= 64; k <<= 1) {
#pragma unroll
    for (int j = k >> 1; j > 0; j >>= 1) {
      unsigned o = __shfl_xor(v, j, 64);
      bool keepmax = (((lane & k) == 0) == ((lane & j) == 0));
      unsigned mx = h2max_u(v, o), mn = h2min_u(v, o);
      v = keepmax ? mx : mn;
    }
  }
  return v;
}
// Merge two descending sorted 64-lists (packed), keep top-64, descending.
__device__ __forceinline__ unsigned bmerge64_h2(unsigned a, unsigned b, int lane) {
  unsigned rb = __shfl(b, 63 - lane, 64);
  unsigned m = h2max_u(a, rb);
#pragma unroll
  for (int j = 32; j > 0; j >>= 1) {
    unsigned o = __shfl_xor(m, j, 64);
    unsigned mx = h2max_u(m, o), mn = h2min_u(m, o);
    m = ((lane & j) == 0) ? mx : mn;
  }
  return m;
}

// ---------------------------------------------------------------------------
// Fused 3-layer conv via bf16 MFMA + packed-pair in-wave bitonic top-50.
// (Round-10 verified conv core, unchanged.)
// ---------------------------------------------------------------------------
__global__ __launch_bounds__(256) void conv_fused_kernel(
    const int* __restrict__ inputs, const unsigned short* __restrict__ emb16,
    const float* __restrict__ b1, const float* __restrict__ b2,
    const float* __restrict__ b3,
    const unsigned short* __restrict__ bh,
    float* __restrict__ cand /* [NBS*10][NCHK][50] */) {
  __shared__ unsigned short plane[ROWS * RS];   // 25.7 KB

  int blk = blockIdx.x;
  int bs = blk / NCHK;
  int chunk = blk - bs * NCHK;
  int base = chunk * CHUNK;
  int tid = threadIdx.x;
  int lane = tid & 63, wave = tid >> 6;

  // ---- gather: copy bf16 emb rows for seq [base-32, base+504) ----
  const int* tokp = inputs + bs * LSEQ;
  for (int i = tid; i < ROWS; i += 256) {
    int seq = base - 32 + i;
    v8s lo8 = (v8s)0, hi8 = (v8s)0;
    if ((unsigned)seq < (unsigned)LSEQ) {
      int tok = tokp[seq];
      const v8s* er = reinterpret_cast<const v8s*>(emb16 + tok * 16);
      lo8 = er[0];
      hi8 = er[1];
    }
    *reinterpret_cast<v8s*>(&plane[i * RS + 0]) = lo8;
    *reinterpret_cast<v8s*>(&plane[i * RS + 8]) = hi8;
  }
  __syncthreads();

  // lane-constant A address part: row (l&15)+(l>>5)+22 (incl +32 plane offset,
  // -10 kh shift), elem offset wi0 = ((l>>4)&1)*8.
  const int laneA = ((lane & 15) + (lane >> 5) + 22) * RS + ((lane >> 4) & 1) * 8;
  const int col = lane & 15;
  const int rbase = (lane >> 4) * 4;

#pragma unroll 1
  for (int stage = 0; stage < 3; ++stage) {
    const int lo = (stage == 0) ? -20 : (stage == 1) ? -10 : 0;
    const int ntiles = (stage == 0) ? 32 : (stage == 1) ? 30 : 28;
    const float bias = (stage == 0) ? b1[0] : (stage == 1) ? b2[0] : b3[0];
    const int nt = (ntiles - wave + 3) >> 2;     // tiles wave+4m, m<nt

    v4f acc[8];
#pragma unroll
    for (int m = 0; m < 8; ++m)
#pragma unroll
      for (int j = 0; j < 4; ++j) acc[m][j] = 0.0f;

    const v8s* bhf = reinterpret_cast<const v8s*>(bh) + (stage * 11) * 64 + lane;
    v8s bhc = bhf[0];

#pragma unroll 1
    for (int t = 0; t < 11; ++t) {
      v8s bhn = bhc;
      if (t < 10) bhn = bhf[(t + 1) * 64];
      const int toff = laneA + t * 2 * RS;
#pragma unroll
      for (int m = 0; m < 8; ++m) {
        if (m < nt) {
          int r0 = lo + (wave + 4 * m) * 16;
          v8s a = *reinterpret_cast<const v8s*>(&plane[toff + r0 * RS]);
          acc[m] = __builtin_amdgcn_mfma_f32_16x16x32_bf16(a, bhc, acc[m], 0, 0, 0);
        }
      }
      bhc = bhn;
    }
    __syncthreads();   // all reads complete before in-place writes

#pragma unroll
    for (int m = 0; m < 8; ++m) {
      if (m < nt) {
        int r0 = lo + (wave + 4 * m) * 16;
#pragma unroll
        for (int j = 0; j < 4; ++j) {
          int rloc = r0 + rbase + j;
          int seq = base + rloc;
          unsigned short us = cvt_bf16(fmaxf(acc[m][j] + bias, 0.0f));
          bool ok = (col < 10) && ((unsigned)seq < (unsigned)LSEQ);
          plane[(rloc + 32) * RS + col] = ok ? us : (unsigned short)0;
        }
      }
    }
    __syncthreads();
  }

  // ---- per-chunk exact top-50, two channels per packed stream ----
  // 5 streams p (cols 2p, 2p+1); 448 vals = 7 segs of 64.
  for (int p = wave; p < 5; p += 4) {          // wave-uniform trip count
    unsigned x[7];
#pragma unroll
    for (int s = 0; s < 7; ++s) {
      unsigned w = *reinterpret_cast<const unsigned*>(
          &plane[(32 + s * 64 + lane) * RS + 2 * p]);
      float flo = __uint_as_float(w << 16);          // bf16 lo -> f32 (exact)
      float fhi = __uint_as_float(w & 0xFFFF0000u);  // bf16 hi -> f32 (exact)
      hf2 h;
      h[0] = (_Float16)flo;                          // f32 -> f16 (exact here)
      h[1] = (_Float16)fhi;
      x[s] = __builtin_bit_cast(unsigned, h);
    }
#pragma unroll
    for (int s = 0; s < 7; ++s) x[s] = bsort64_h2(x[s], lane);
    unsigned y0 = bmerge64_h2(x[0], x[1], lane);
    unsigned y1 = bmerge64_h2(x[2], x[3], lane);
    unsigned y2 = bmerge64_h2(x[4], x[5], lane);
    unsigned z0 = bmerge64_h2(y0, y1, lane);
    unsigned z1 = bmerge64_h2(y2, x[6], lane);
    unsigned t  = bmerge64_h2(z0, z1, lane);
    if (lane < 50) {
      hf2 h = __builtin_bit_cast(hf2, t);
      cand[((bs * 10 + 2 * p + 0) * NCHK + chunk) * 50 + lane] = (float)h[0];
      cand[((bs * 10 + 2 * p + 1) * NCHK + chunk) * 50 + lane] = (float)h[1];
    }
  }
}

// ---------------------------------------------------------------------------
// Merge: per (bs, d), top-50 (sorted desc) of 37*50=1850 chunk candidates.
// ---------------------------------------------------------------------------
__global__ __launch_bounds__(256) void merge_topk_kernel(
    const float* __restrict__ cand, float* __restrict__ fbuf) {
  __shared__ float ml[2048];
  int blk = blockIdx.x;            // bs*10 + d
  int tid = threadIdx.x;
  const float* src = cand + blk * (NCHK * 50);
  for (int i = tid; i < 2048; i += 256) ml[i] = (i < NCHK * 50) ? src[i] : -1.0f;
  for (int k = 2; k <= 2048; k <<= 1) {
    for (int j = k >> 1; j > 0; j >>= 1) {
      __syncthreads();
      for (int e = tid; e < 1024; e += 256) {
        int lo = ((e & ~(j - 1)) << 1) | (e & (j - 1));
        int hi = lo | j;
        float a = ml[lo], b = ml[hi];
        bool desc = ((lo & k) == 0);
        if ((a < b) == desc) { ml[lo] = b; ml[hi] = a; }
      }
    }
  }
  __syncthreads();
  if (tid < 50) {
    int bs = blk / 10, d = blk - bs * 10;
    fbuf[bs * 500 + tid * 10 + d] = ml[tid];
  }
}

// ---------------------------------------------------------------------------
// Per-(batch, direction) MHA + sum over queries + final dense + softmax.
// ---------------------------------------------------------------------------
__global__ __launch_bounds__(256) void mha_kernel(
    const float* __restrict__ fbuf,
    const float* __restrict__ wq, const float* __restrict__ bq,
    const float* __restrict__ wk, const float* __restrict__ bk,
    const float* __restrict__ wv, const float* __restrict__ bv,
    const float* __restrict__ wo, const float* __restrict__ bo,
    const float* __restrict__ wf, const float* __restrict__ bf,
    float* __restrict__ out) {
  __shared__ float f[2][50][10];
  __shared__ float Qm[50][2][10];
  __shared__ float Km[50][2][10];
  __shared__ float Vm[50][2][10];
  __shared__ float A2[2][50][50];
  __shared__ float Abar[2][50];
  __shared__ float OS[2][10];
  __shared__ float rr[10];

  int blk = blockIdx.x, b = blk >> 1, dir = blk & 1;
  int qs = dir, ks = dir ^ 1;
  int tid = threadIdx.x;

  for (int i = tid; i < 1000; i += 256) (&f[0][0][0])[i] = fbuf[b * 1000 + i];
  __syncthreads();

  for (int i = tid; i < 1000; i += 256) {
    int q = i / 20, rem = i - q * 20;
    int h = rem / 10, e = rem - h * 10;
    const float* fq = f[qs][q];
    const float* fk = f[ks][q];
    float aq = bq[h * 10 + e], ak = bk[h * 10 + e], av = bv[h * 10 + e];
#pragma unroll
    for (int dd = 0; dd < 10; ++dd) {
      int wIdx = dd * 20 + h * 10 + e;
      aq = fmaf(fq[dd], wq[wIdx], aq);
      ak = fmaf(fk[dd], wk[wIdx], ak);
      av = fmaf(fk[dd], wv[wIdx], av);
    }
    Qm[q][h][e] = aq; Km[q][h][e] = ak; Vm[q][h][e] = av;
  }
  __syncthreads();

  for (int row = tid; row < 100; row += 256) {
    int h = row / 50, q = row - h * 50;
    const float* Qr = Qm[q][h];
    float lg[50], m = -1e30f;
#pragma unroll
    for (int s = 0; s < 50; ++s) {
      const float* Kr = Km[s][h];
      float t = 0.0f;
#pragma unroll
      for (int e = 0; e < 10; ++e) t = fmaf(Qr[e], Kr[e], t);
      t *= 0.31622776601683794f;   // 1/sqrt(10)
      lg[s] = t; m = fmaxf(m, t);
    }
    float sum = 0.0f;
#pragma unroll
    for (int s = 0; s < 50; ++s) { float p = __expf(lg[s] - m); lg[s] = p; sum += p; }
    float inv = 1.0f / sum;
#pragma unroll
    for (int s = 0; s < 50; ++s) A2[h][q][s] = lg[s] * inv;
  }
  __syncthreads();

  for (int i = tid; i < 100; i += 256) {
    int h = i / 50, s = i - h * 50;
    float t = 0.0f;
#pragma unroll
    for (int q = 0; q < 50; ++q) t += A2[h][q][s];
    Abar[h][s] = t;
  }
  __syncthreads();
  if (tid < 20) {
    int h = tid / 10, e = tid - h * 10;
    float t = 0.0f;
#pragma unroll
    for (int s = 0; s < 50; ++s) t += Abar[h][s] * Vm[s][h][e];
    OS[h][e] = t;
  }
  __syncthreads();
  if (tid < 10) {
    int dc = tid;
    float t = 50.0f * bo[dc];
#pragma unroll
    for (int h = 0; h < 2; ++h)
#pragma unroll
      for (int e = 0; e < 10; ++e) t = fmaf(OS[h][e], wo[h * 100 + e * 10 + dc], t);
    rr[dc] = t;
  }
  __syncthreads();
  if (tid == 0) {
    float l0 = bf[0], l1 = bf[1];
#pragma unroll
    for (int dd = 0; dd < 10; ++dd) {
      l0 = fmaf(rr[dd], wf[dd * 2 + 0], l0);
      l1 = fmaf(rr[dd], wf[dd * 2 + 1], l1);
    }
    float m = fmaxf(l0, l1);
    float e0 = expf(l0 - m), e1 = expf(l1 - m);
    float inv = 1.0f / (e0 + e1);
    out[(b * 2 + dir) * 2 + 0] = e0 * inv;
    out[(b * 2 + dir) * 2 + 1] = e1 * inv;
  }
}

// ---------------------------------------------------------------------------
extern "C" void kernel_launch(void* const* d_in, const int* in_sizes, int n_in,
                              void* d_out, int out_size, void* d_ws, size_t ws_size,
                              hipStream_t stream) {
  const int*   inputs = (const int*)d_in[0];
  const float* emb = (const float*)d_in[1];
  const float* w1 = (const float*)d_in[2];
  const float* b1 = (const float*)d_in[3];
  const float* w2 = (const float*)d_in[4];
  const float* b2 = (const float*)d_in[5];
  const float* w3 = (const float*)d_in[6];
  const float* b3 = (const float*)d_in[7];
  const float* wq = (const float*)d_in[8];
  const float* bq = (const float*)d_in[9];
  const float* wk = (const float*)d_in[10];
  const float* bk = (const float*)d_in[11];
  const float* wv = (const float*)d_in[12];
  const float* bv = (const float*)d_in[13];
  const float* wo = (const float*)d_in[14];
  const float* bo = (const float*)d_in[15];
  const float* wf = (const float*)d_in[16];
  const float* bf = (const float*)d_in[17];
  float* out = (float*)d_out;

  float* fbuf = (float*)d_ws;                         // 32768 f32
  float* cand = (float*)d_ws + 32768;                 // 640*37*50 = 1,184,000 f32
  unsigned short* bh = (unsigned short*)((float*)d_ws + 1216768);   // 16896 u16
  unsigned short* emb16 = bh + 16896;                 // 8001*16 u16 (16B-aligned)

  hipLaunchKernelGGL(emb16_kernel, dim3(32), dim3(256), 0, stream, emb, emb16);
  hipLaunchKernelGGL(bfrag_kernel, dim3(9), dim3(256), 0, stream, w1, w2, w3, bh);
  hipLaunchKernelGGL(conv_fused_kernel, dim3(NBS * NCHK), dim3(256), 0, stream,
                     inputs, emb16, b1, b2, b3, bh, cand);
  hipLaunchKernelGGL(merge_topk_kernel, dim3(NBS * 10), dim3(256), 0, stream, cand, fbuf);
  hipLaunchKernelGGL(mha_kernel, dim3(NBS), dim3(256), 0, stream,
                     fbuf, wq, bq, wk, bk, wv, bv, wo, bo, wf, bf, out);
}

// Round 13
// 122.802 us; speedup vs baseline: 2.0748x; 1.4158x over previous
//
#include <hip/hip_runtime.h>
#include <hip/hip_bf16.h>

#define LSEQ   16384
#define BATCH  32
#define NBS    64              // B*2 sequences
#define NW     8000
#define CHUNK  448             // output rows per block
#define NCHK   37              // ceil(16384/448)
#define ROWS   536             // LDS plane rows: seq [base-32, base+504)
#define RS     24              // row stride in ushorts (48 B: 16 bf16 data + 8 pad)

typedef short v8s __attribute__((ext_vector_type(8)));   // 8 bf16 = 4 VGPR
typedef float v4f __attribute__((ext_vector_type(4)));   // MFMA acc
typedef _Float16 hf2 __attribute__((ext_vector_type(2)));  // packed f16 pair

__device__ __forceinline__ unsigned short f2bf(float f) {   // RTNE f32->bf16
  unsigned u = __float_as_uint(f);
  unsigned r = u + 0x7FFFu + ((u >> 16) & 1u);
  return (unsigned short)(r >> 16);
}
__device__ __forceinline__ unsigned short cvt_bf16(float v) {  // HW cvt
  __hip_bfloat16 hb = __float2bfloat16(v);
  unsigned short us;
  __builtin_memcpy(&us, &hb, 2);
  return us;
}

// ---------------------------------------------------------------------------
// Fused one-time prep: blocks 0..31 build the bf16 emb table [NW+1][16];
// blocks 32..40 build the MFMA B-fragments.
// B[k=kh*16+wi][n] = W[kh][wi-n+10] (0 outside / n>=10); B-operand layout:
// lane l holds B[k=32t+(l>>4)*8+j][col=l&15], j=0..7.
// ---------------------------------------------------------------------------
__global__ __launch_bounds__(256) void prep_kernel(
    const float* __restrict__ emb, const float* __restrict__ w1,
    const float* __restrict__ w2, const float* __restrict__ w3,
    unsigned short* __restrict__ emb16, unsigned short* __restrict__ bh) {
  int bid = blockIdx.x;
  if (bid < 32) {
    int r = bid * 256 + threadIdx.x;
    if (r > NW) return;
    const float2* er = reinterpret_cast<const float2*>(emb + r * 10);
    float v[10];
#pragma unroll
    for (int k = 0; k < 5; ++k) { float2 t2 = er[k]; v[2 * k] = t2.x; v[2 * k + 1] = t2.y; }
    v8s lo8 = (v8s)0, hi8 = (v8s)0;
#pragma unroll
    for (int j = 0; j < 8; ++j) lo8[j] = (short)f2bf(v[j]);
    hi8[0] = (short)f2bf(v[8]);
    hi8[1] = (short)f2bf(v[9]);
    v8s* dst = reinterpret_cast<v8s*>(emb16 + r * 16);
    dst[0] = lo8;
    dst[1] = hi8;
  } else {
    int idx = (bid - 32) * 256 + threadIdx.x;   // (stage*11 + t)*64 + lane
    if (idx >= 3 * 11 * 64) return;
    int lane = idx & 63, rest = idx >> 6;
    int t = rest % 11, stage = rest / 11;
    const float* W = (stage == 0) ? w1 : (stage == 1) ? w2 : w3;
    int col = lane & 15;
    int kh = 2 * t + (lane >> 5);
    int wi0 = ((lane >> 4) & 1) * 8;
#pragma unroll
    for (int j = 0; j < 8; ++j) {
      int wi = wi0 + j;
      int kw = wi - col + 10;
      float v = (wi < 10 && col < 10 && kw >= 0 && kw < 22) ? W[kh * 22 + kw] : 0.0f;
      bh[idx * 8 + j] = f2bf(v);
    }
  }
}

// ---------------------------------------------------------------------------
// Packed-pair (two channels per u32, f16x2) bitonic primitives.
// Post-relu values are >=0 and << 65504, and already bf16-quantized, so
// bf16 -> f16 is EXACT and order-preserving. __builtin_elementwise_max/min
// on native f16x2 lower to v_pk_max_f16 / v_pk_min_f16.
// ---------------------------------------------------------------------------
__device__ __forceinline__ unsigned h2max_u(unsigned a, unsigned b) {
  hf2 r = __builtin_elementwise_max(__builtin_bit_cast(hf2, a),
                                    __builtin_bit_cast(hf2, b));
  return __builtin_bit_cast(unsigned, r);
}
__device__ __forceinline__ unsigned h2min_u(unsigned a, unsigned b) {
  hf2 r = __builtin_elementwise_min(__builtin_bit_cast(hf2, a),
                                    __builtin_bit_cast(hf2, b));
  return __builtin_bit_cast(unsigned, r);
}

// Sort 64 packed pairs across the wave, both halves descending.
__device__ __forceinline__ unsigned bsort64_h2(unsigned v, int lane) {
#pragma unroll
  for (int k = 2; k <= 64; k <<= 1) {
#pragma unroll
    for (int j = k >> 1; j > 0; j >>= 1) {
      unsigned o = __shfl_xor(v, j, 64);
      bool keepmax = (((lane & k) == 0) == ((lane & j) == 0));
      unsigned mx = h2max_u(v, o), mn = h2min_u(v, o);
      v = keepmax ? mx : mn;
    }
  }
  return v;
}
// Merge two descending sorted 64-lists (packed), keep top-64, descending.
__device__ __forceinline__ unsigned bmerge64_h2(unsigned a, unsigned b, int lane) {
  unsigned rb = __shfl(b, 63 - lane, 64);
  unsigned m = h2max_u(a, rb);
#pragma unroll
  for (int j = 32; j > 0; j >>= 1) {
    unsigned o = __shfl_xor(m, j, 64);
    unsigned mx = h2max_u(m, o), mn = h2min_u(m, o);
    m = ((lane & j) == 0) ? mx : mn;
  }
  return m;
}

// ---------------------------------------------------------------------------
// Fused 3-layer conv via bf16 MFMA + packed-pair in-wave bitonic top-50.
// 512 threads (8 waves) per chunk: per-wave tiles halve (nt<=4, acc 16 VGPR),
// 3-4 blocks/CU co-resident (24-32 waves/CU) hide the 7-barrier in-place
// structure that capped round 12 at 26% occupancy. Top-k streams map 1:1
// onto waves 0..4. Candidates emitted PACKED (u32 = f16 ch-pair).
// ---------------------------------------------------------------------------
__global__ __launch_bounds__(512, 6) void conv_fused_kernel(
    const int* __restrict__ inputs, const unsigned short* __restrict__ emb16,
    const float* __restrict__ b1, const float* __restrict__ b2,
    const float* __restrict__ b3,
    const unsigned short* __restrict__ bh,
    unsigned* __restrict__ candp /* [NBS*5][NCHK][50] packed */) {
  __shared__ unsigned short plane[ROWS * RS];   // 25.7 KB

  int blk = blockIdx.x;
  int bs = blk / NCHK;
  int chunk = blk - bs * NCHK;
  int base = chunk * CHUNK;
  int tid = threadIdx.x;
  int lane = tid & 63, wave = tid >> 6;

  // ---- gather: copy bf16 emb rows for seq [base-32, base+504) ----
  const int* tokp = inputs + bs * LSEQ;
  for (int i = tid; i < ROWS; i += 512) {
    int seq = base - 32 + i;
    v8s lo8 = (v8s)0, hi8 = (v8s)0;
    if ((unsigned)seq < (unsigned)LSEQ) {
      int tok = tokp[seq];
      const v8s* er = reinterpret_cast<const v8s*>(emb16 + tok * 16);
      lo8 = er[0];
      hi8 = er[1];
    }
    *reinterpret_cast<v8s*>(&plane[i * RS + 0]) = lo8;
    *reinterpret_cast<v8s*>(&plane[i * RS + 8]) = hi8;
  }
  __syncthreads();

  // lane-constant A address part: row (l&15)+(l>>5)+22 (incl +32 plane offset,
  // -10 kh shift), elem offset wi0 = ((l>>4)&1)*8.
  const int laneA = ((lane & 15) + (lane >> 5) + 22) * RS + ((lane >> 4) & 1) * 8;
  const int col = lane & 15;
  const int rbase = (lane >> 4) * 4;

#pragma unroll 1
  for (int stage = 0; stage < 3; ++stage) {
    const int lo = (stage == 0) ? -20 : (stage == 1) ? -10 : 0;
    const int ntiles = (stage == 0) ? 32 : (stage == 1) ? 30 : 28;
    const float bias = (stage == 0) ? b1[0] : (stage == 1) ? b2[0] : b3[0];
    const int nt = (ntiles - wave + 7) >> 3;     // tiles wave+8m, m<nt

    v4f acc[4];
#pragma unroll
    for (int m = 0; m < 4; ++m)
#pragma unroll
      for (int j = 0; j < 4; ++j) acc[m][j] = 0.0f;

    const v8s* bhf = reinterpret_cast<const v8s*>(bh) + (stage * 11) * 64 + lane;
    v8s bhc = bhf[0];

#pragma unroll 1
    for (int t = 0; t < 11; ++t) {
      v8s bhn = bhc;
      if (t < 10) bhn = bhf[(t + 1) * 64];
      const int toff = laneA + t * 2 * RS;
#pragma unroll
      for (int m = 0; m < 4; ++m) {
        if (m < nt) {
          int r0 = lo + (wave + 8 * m) * 16;
          v8s a = *reinterpret_cast<const v8s*>(&plane[toff + r0 * RS]);
          acc[m] = __builtin_amdgcn_mfma_f32_16x16x32_bf16(a, bhc, acc[m], 0, 0, 0);
        }
      }
      bhc = bhn;
    }
    __syncthreads();   // all reads complete before in-place writes

#pragma unroll
    for (int m = 0; m < 4; ++m) {
      if (m < nt) {
        int r0 = lo + (wave + 8 * m) * 16;
#pragma unroll
        for (int j = 0; j < 4; ++j) {
          int rloc = r0 + rbase + j;
          int seq = base + rloc;
          unsigned short us = cvt_bf16(fmaxf(acc[m][j] + bias, 0.0f));
          bool ok = (col < 10) && ((unsigned)seq < (unsigned)LSEQ);
          plane[(rloc + 32) * RS + col] = ok ? us : (unsigned short)0;
        }
      }
    }
    __syncthreads();
  }

  // ---- per-chunk exact top-50, one packed channel-pair stream per wave ----
  if (wave < 5) {
    int p = wave;                              // cols 2p, 2p+1
    unsigned x[7];
#pragma unroll
    for (int s = 0; s < 7; ++s) {
      unsigned w = *reinterpret_cast<const unsigned*>(
          &plane[(32 + s * 64 + lane) * RS + 2 * p]);
      float flo = __uint_as_float(w << 16);          // bf16 lo -> f32 (exact)
      float fhi = __uint_as_float(w & 0xFFFF0000u);  // bf16 hi -> f32 (exact)
      hf2 h;
      h[0] = (_Float16)flo;                          // f32 -> f16 (exact here)
      h[1] = (_Float16)fhi;
      x[s] = __builtin_bit_cast(unsigned, h);
    }
#pragma unroll
    for (int s = 0; s < 7; ++s) x[s] = bsort64_h2(x[s], lane);
    unsigned y0 = bmerge64_h2(x[0], x[1], lane);
    unsigned y1 = bmerge64_h2(x[2], x[3], lane);
    unsigned y2 = bmerge64_h2(x[4], x[5], lane);
    unsigned z0 = bmerge64_h2(y0, y1, lane);
    unsigned z1 = bmerge64_h2(y2, x[6], lane);
    unsigned t  = bmerge64_h2(z0, z1, lane);
    if (lane < 50)
      candp[((bs * 5 + p) * NCHK + chunk) * 50 + lane] = t;
  }
}

// ---------------------------------------------------------------------------
// Merge: per (bs, channel-pair), top-50 of 37*50=1850 packed candidates.
// Packed bitonic-2048 (both halves sorted descending simultaneously);
// unpack only when writing fbuf. Pad = 0x0 (f16 zero) — cannot outrank any
// real value, ties with real zeros are value-identical.
// ---------------------------------------------------------------------------
__global__ __launch_bounds__(256) void merge_topk_kernel(
    const unsigned* __restrict__ candp, float* __restrict__ fbuf) {
  __shared__ unsigned ml[2048];
  int blk = blockIdx.x;            // bs*5 + p
  int tid = threadIdx.x;
  const unsigned* src = candp + blk * (NCHK * 50);
  for (int i = tid; i < 2048; i += 256) ml[i] = (i < NCHK * 50) ? src[i] : 0u;
  for (int k = 2; k <= 2048; k <<= 1) {
    for (int j = k >> 1; j > 0; j >>= 1) {
      __syncthreads();
      for (int e = tid; e < 1024; e += 256) {
        int lo = ((e & ~(j - 1)) << 1) | (e & (j - 1));
        int hi = lo | j;
        unsigned a = ml[lo], b = ml[hi];
        bool desc = ((lo & k) == 0);
        unsigned mx = h2max_u(a, b), mn = h2min_u(a, b);
        ml[lo] = desc ? mx : mn;
        ml[hi] = desc ? mn : mx;
      }
    }
  }
  __syncthreads();
  if (tid < 50) {
    int bs = blk / 5, p = blk - bs * 5;
    hf2 h = __builtin_bit_cast(hf2, ml[tid]);
    fbuf[bs * 500 + tid * 10 + 2 * p + 0] = (float)h[0];
    fbuf[bs * 500 + tid * 10 + 2 * p + 1] = (float)h[1];
  }
}

// ---------------------------------------------------------------------------
// Per-(batch, direction) MHA + sum over queries + final dense + softmax.
// ---------------------------------------------------------------------------
__global__ __launch_bounds__(256) void mha_kernel(
    const float* __restrict__ fbuf,
    const float* __restrict__ wq, const float* __restrict__ bq,
    const float* __restrict__ wk, const float* __restrict__ bk,
    const float* __restrict__ wv, const float* __restrict__ bv,
    const float* __restrict__ wo, const float* __restrict__ bo,
    const float* __restrict__ wf, const float* __restrict__ bf,
    float* __restrict__ out) {
  __shared__ float f[2][50][10];
  __shared__ float Qm[50][2][10];
  __shared__ float Km[50][2][10];
  __shared__ float Vm[50][2][10];
  __shared__ float A2[2][50][50];
  __shared__ float Abar[2][50];
  __shared__ float OS[2][10];
  __shared__ float rr[10];

  int blk = blockIdx.x, b = blk >> 1, dir = blk & 1;
  int qs = dir, ks = dir ^ 1;
  int tid = threadIdx.x;

  for (int i = tid; i < 1000; i += 256) (&f[0][0][0])[i] = fbuf[b * 1000 + i];
  __syncthreads();

  for (int i = tid; i < 1000; i += 256) {
    int q = i / 20, rem = i - q * 20;
    int h = rem / 10, e = rem - h * 10;
    const float* fq = f[qs][q];
    const float* fk = f[ks][q];
    float aq = bq[h * 10 + e], ak = bk[h * 10 + e], av = bv[h * 10 + e];
#pragma unroll
    for (int dd = 0; dd < 10; ++dd) {
      int wIdx = dd * 20 + h * 10 + e;
      aq = fmaf(fq[dd], wq[wIdx], aq);
      ak = fmaf(fk[dd], wk[wIdx], ak);
      av = fmaf(fk[dd], wv[wIdx], av);
    }
    Qm[q][h][e] = aq; Km[q][h][e] = ak; Vm[q][h][e] = av;
  }
  __syncthreads();

  for (int row = tid; row < 100; row += 256) {
    int h = row / 50, q = row - h * 50;
    const float* Qr = Qm[q][h];
    float lg[50], m = -1e30f;
#pragma unroll
    for (int s = 0; s < 50; ++s) {
      const float* Kr = Km[s][h];
      float t = 0.0f;
#pragma unroll
      for (int e = 0; e < 10; ++e) t = fmaf(Qr[e], Kr[e], t);
      t *= 0.31622776601683794f;   // 1/sqrt(10)
      lg[s] = t; m = fmaxf(m, t);
    }
    float sum = 0.0f;
#pragma unroll
    for (int s = 0; s < 50; ++s) { float p = __expf(lg[s] - m); lg[s] = p; sum += p; }
    float inv = 1.0f / sum;
#pragma unroll
    for (int s = 0; s < 50; ++s) A2[h][q][s] = lg[s] * inv;
  }
  __syncthreads();

  for (int i = tid; i < 100; i += 256) {
    int h = i / 50, s = i - h * 50;
    float t = 0.0f;
#pragma unroll
    for (int q = 0; q < 50; ++q) t += A2[h][q][s];
    Abar[h][s] = t;
  }
  __syncthreads();
  if (tid < 20) {
    int h = tid / 10, e = tid - h * 10;
    float t = 0.0f;
#pragma unroll
    for (int s = 0; s < 50; ++s) t += Abar[h][s] * Vm[s][h][e];
    OS[h][e] = t;
  }
  __syncthreads();
  if (tid < 10) {
    int dc = tid;
    float t = 50.0f * bo[dc];
#pragma unroll
    for (int h = 0; h < 2; ++h)
#pragma unroll
      for (int e = 0; e < 10; ++e) t = fmaf(OS[h][e], wo[h * 100 + e * 10 + dc], t);
    rr[dc] = t;
  }
  __syncthreads();
  if (tid == 0) {
    float l0 = bf[0], l1 = bf[1];
#pragma unroll
    for (int dd = 0; dd < 10; ++dd) {
      l0 = fmaf(rr[dd], wf[dd * 2 + 0], l0);
      l1 = fmaf(rr[dd], wf[dd * 2 + 1], l1);
    }
    float m = fmaxf(l0, l1);
    float e0 = expf(l0 - m), e1 = expf(l1 - m);
    float inv = 1.0f / (e0 + e1);
    out[(b * 2 + dir) * 2 + 0] = e0 * inv;
    out[(b * 2 + dir) * 2 + 1] = e1 * inv;
  }
}

// ---------------------------------------------------------------------------
extern "C" void kernel_launch(void* const* d_in, const int* in_sizes, int n_in,
                              void* d_out, int out_size, void* d_ws, size_t ws_size,
                              hipStream_t stream) {
  const int*   inputs = (const int*)d_in[0];
  const float* emb = (const float*)d_in[1];
  const float* w1 = (const float*)d_in[2];
  const float* b1 = (const float*)d_in[3];
  const float* w2 = (const float*)d_in[4];
  const float* b2 = (const float*)d_in[5];
  const float* w3 = (const float*)d_in[6];
  const float* b3 = (const float*)d_in[7];
  const float* wq = (const float*)d_in[8];
  const float* bq = (const float*)d_in[9];
  const float* wk = (const float*)d_in[10];
  const float* bk = (const float*)d_in[11];
  const float* wv = (const float*)d_in[12];
  const float* bv = (const float*)d_in[13];
  const float* wo = (const float*)d_in[14];
  const float* bo = (const float*)d_in[15];
  const float* wf = (const float*)d_in[16];
  const float* bf = (const float*)d_in[17];
  float* out = (float*)d_out;

  float* fbuf = (float*)d_ws;                         // 32768 f32
  unsigned* candp = (unsigned*)((float*)d_ws + 32768);   // 64*5*37*50 = 592,000 u32
  unsigned short* bh = (unsigned short*)((float*)d_ws + 1216768);   // 16896 u16
  unsigned short* emb16 = bh + 16896;                 // 8001*16 u16 (16B-aligned)

  hipLaunchKernelGGL(prep_kernel, dim3(41), dim3(256), 0, stream,
                     emb, w1, w2, w3, emb16, bh);
  hipLaunchKernelGGL(conv_fused_kernel, dim3(NBS * NCHK), dim3(512), 0, stream,
                     inputs, emb16, b1, b2, b3, bh, candp);
  hipLaunchKernelGGL(merge_topk_kernel, dim3(NBS * 5), dim3(256), 0, stream, candp, fbuf);
  hipLaunchKernelGGL(mha_kernel, dim3(NBS), dim3(256), 0, stream,
                     fbuf, wq, bq, wk, bk, wv, bv, wo, bo, wf, bf, out);
}